// Round 2
// baseline (2474.531 us; speedup 1.0000x reference)
//
#include <hip/hip_runtime.h>
#include <math.h>

#define NN 50000
#define MP 50048          // NN padded to multiple of 128 (32 rows x 4 waves)
#define NE 800000
#define FIN 64
#define HD 200
#define NG 256
#define SCAN_B 256
#define KPAD 224          // HD padded to multiple of 32 for MFMA K-steps
#define NT 13             // 13 * 16 = 208 >= 200 output col tiles
#define HB 12544          // LDS histogram packed dwords (covers 25088 nodes/pass)
#define PER_B 3125        // NE / 256 edges per histogram block

typedef _Float16 h16;
typedef __attribute__((ext_vector_type(8))) _Float16 half8;
typedef __attribute__((ext_vector_type(4))) float float4v;
typedef unsigned long long u64;

// ---------- dual histogram: blocks 0-255 src -> pSrc, 256-511 dst -> pDst ----------
__global__ __launch_bounds__(256) void k_hist(const int* __restrict__ src,
                                              const int* __restrict__ dst,
                                              unsigned* __restrict__ pSrc,
                                              unsigned* __restrict__ pDst, int E) {
    __shared__ unsigned h[HB];
    int tid = threadIdx.x;
    int isDst = blockIdx.x >> 8;
    int b = blockIdx.x & 255;
    const int* idx = isDst ? dst : src;
    unsigned* partial = isDst ? pDst : pSrc;
    int e0 = b * PER_B;
    int v[13];
#pragma unroll
    for (int j = 0; j < 13; ++j) {
        int o = j * 256 + tid;
        v[j] = (o < PER_B) ? idx[e0 + o] : -1;
    }
#pragma unroll
    for (int pass = 0; pass < 2; ++pass) {
        for (int t = tid; t < HB; t += 256) h[t] = 0;
        __syncthreads();
        int lo = pass * (2 * HB);
#pragma unroll
        for (int j = 0; j < 13; ++j) {
            int vv = v[j] - lo;
            if (vv >= 0 && vv < 2 * HB)
                atomicAdd(&h[vv >> 1], (vv & 1) ? 0x10000u : 1u);
        }
        __syncthreads();
        unsigned* pb = partial + ((size_t)pass * 256 + b) * HB;
        for (int t = tid; t < HB; t += 256) pb[t] = h[t];
        __syncthreads();
    }
}

// ---------- fused: reduce src partials -> degi ; scan dst partials -> bases + cntd ----------
__global__ void k_hredscan(const unsigned* __restrict__ pSrc, unsigned* __restrict__ pDst,
                           int* __restrict__ degi, int* __restrict__ cntd, int n) {
    int i = blockIdx.x * blockDim.x + threadIdx.x;
    if (i < 2 * HB) {
        int pass = i / HB, p = i - pass * HB;
        const unsigned* pb = pSrc + (size_t)pass * 256 * HB + p;
        unsigned s = 0;
        for (int b = 0; b < 256; ++b) s += pb[(size_t)b * HB];
        int n0 = pass * 2 * HB + 2 * p;
        if (n0 < n)     degi[n0]     = (int)(s & 0xffffu);
        if (n0 + 1 < n) degi[n0 + 1] = (int)(s >> 16);
    } else if (i < 4 * HB) {
        int j = i - 2 * HB;
        int pass = j / HB, p = j - pass * HB;
        unsigned* pb = pDst + (size_t)pass * 256 * HB + p;
        unsigned run = 0;
        for (int b = 0; b < 256; ++b) {
            unsigned c = pb[(size_t)b * HB];
            pb[(size_t)b * HB] = run;
            run += c;
        }
        int n0 = pass * 2 * HB + 2 * p;
        if (n0 < n)     cntd[n0]     = (int)(run & 0xffffu);
        if (n0 + 1 < n) cntd[n0 + 1] = (int)(run >> 16);
    }
}

// ---------- fused node prep (dis/qs/diag) + graph bounds + gather-counter zeroing ----------
__global__ void k_prep(const int* __restrict__ degi, const int* __restrict__ batch,
                       const float* __restrict__ lmax, float* __restrict__ dis,
                       float* __restrict__ qs, float* __restrict__ diag,
                       int* __restrict__ gstart, unsigned* __restrict__ ctr,
                       int n, int gN) {
    int b = blockIdx.x;
    if (b < gN) {
        int i = b * 256 + threadIdx.x;
        if (i < n) {
            int d = degi[i];
            float di = (d > 0) ? (1.0f / sqrtf((float)d)) : 0.0f;
            float sc = 2.0f / lmax[batch[i]];
            dis[i] = di;
            qs[i] = -di * sc;
            diag[i] = sc - 1.0f;
        }
    } else if (b == gN + 2) {
        if (threadIdx.x < 64) ctr[threadIdx.x] = 0u;   // 8 launches x 8 group counters
    } else {
        int g = (b - gN) * 256 + threadIdx.x;
        if (g > NG) return;
        if (g == NG) { gstart[NG] = n; return; }
        int lo = 0, hi = n;
        while (lo < hi) {
            int mid = (lo + hi) >> 1;
            if (batch[mid] < g) lo = mid + 1; else hi = mid;
        }
        gstart[g] = lo;
    }
}

// ---------- exclusive scan over cnt_dst (block-local; global base added by consumers) ----------
__global__ void k_scan1(const int* __restrict__ cnt, int* __restrict__ excl,
                        int* __restrict__ bsum, int n) {
    __shared__ int sh[SCAN_B];
    int tid = threadIdx.x;
    int i = blockIdx.x * SCAN_B + tid;
    int v = (i < n) ? cnt[i] : 0;
    sh[tid] = v;
    __syncthreads();
    for (int off = 1; off < SCAN_B; off <<= 1) {
        int t = (tid >= off) ? sh[tid - off] : 0;
        __syncthreads();
        sh[tid] += t;
        __syncthreads();
    }
    if (i < n) excl[i] = sh[tid] - v;
    if (tid == SCAN_B - 1) bsum[blockIdx.x] = sh[tid];
}

__global__ void k_scan2(int* __restrict__ bsum, int nb) {
    __shared__ int sh[SCAN_B];
    int tid = threadIdx.x;
    int v = (tid < nb) ? bsum[tid] : 0;
    sh[tid] = v;
    __syncthreads();
    for (int off = 1; off < SCAN_B; off <<= 1) {
        int t = (tid >= off) ? sh[tid - off] : 0;
        __syncthreads();
        sh[tid] += t;
        __syncthreads();
    }
    if (tid < nb) bsum[tid] = sh[tid] - v;   // exclusive over block totals
}

// ---------- per-node meta: {rowstart:32, cnt:16, diag(fp16):16} packed u64 ----------
__global__ void k_meta(const int* __restrict__ excl, const int* __restrict__ bsum,
                       const int* __restrict__ cntd, const float* __restrict__ diag,
                       u64* __restrict__ meta, int n) {
    int i = blockIdx.x * 256 + threadIdx.x;
    if (i >= n) return;
    unsigned start = (unsigned)(excl[i] + bsum[i >> 8]);
    union { h16 h; unsigned short u; } d;
    d.h = (h16)diag[i];
    meta[i] = (u64)start | ((u64)(unsigned)cntd[i] << 32) | ((u64)d.u << 48);
}

// ---------- CSR fill, zero global atomics. Edge record = u32 {src:16, w:fp16:16} ----------
__global__ __launch_bounds__(256) void k_fillcsr2(
    const int* __restrict__ src, const int* __restrict__ dst,
    const float* __restrict__ qs, const float* __restrict__ dis,
    const int* __restrict__ excl, const int* __restrict__ bsum,
    const unsigned* __restrict__ hpart, unsigned* __restrict__ csr, int E) {
    __shared__ unsigned lrank[HB];
    int tid = threadIdx.x;
    int e0 = blockIdx.x * PER_B;
    int vs[13], vd[13];
#pragma unroll
    for (int j = 0; j < 13; ++j) {
        int o = j * 256 + tid;
        vs[j] = (o < PER_B) ? src[e0 + o] : -1;
        vd[j] = (o < PER_B) ? dst[e0 + o] : -1;
    }
#pragma unroll
    for (int pass = 0; pass < 2; ++pass) {
        for (int t = tid; t < HB; t += 256) lrank[t] = 0;
        __syncthreads();
        int lo = pass * (2 * HB);
        const unsigned* base = hpart + ((size_t)pass * 256 + blockIdx.x) * HB;
#pragma unroll
        for (int j = 0; j < 13; ++j) {
            int vv = vd[j] - lo;
            if (vv >= 0 && vv < 2 * HB) {
                unsigned old = atomicAdd(&lrank[vv >> 1], (vv & 1) ? 0x10000u : 1u);
                unsigned rank = (vv & 1) ? (old >> 16) : (old & 0xffffu);
                unsigned bs = base[vv >> 1];
                unsigned bb = (vv & 1) ? (bs >> 16) : (bs & 0xffffu);
                int s = vs[j], d = vd[j];
                int pos = excl[d] + bsum[d >> 8] + (int)bb + (int)rank;
                union { h16 h; unsigned short u; } cw;
                cw.h = (h16)(qs[s] * dis[d]);
                csr[pos] = (unsigned)s | ((unsigned)cw.u << 16);
            }
        }
        __syncthreads();
    }
}

// ---------- W pre-transpose (Chebyshev fold) + x fp32->fp16 + hi0 pad-col zeroing ----------
// out = Tx0*(W0-W2) + Tx1*W1 + prop(Tx1)*(2*W2): gathers are pure props.
// fp16 [seg][ks][208][32]; B k-pads ZERO; hi0 cols [200,224) zeroed once so layer-1
// gather input pads are finite (A-pad x B-zero stays zero in MFMA).
__global__ void k_wprep(const float* __restrict__ W1, const float* __restrict__ W2,
                        const float* __restrict__ W3, const float* __restrict__ W4,
                        h16* __restrict__ wt0, h16* __restrict__ wt1,
                        h16* __restrict__ wt2, h16* __restrict__ wt3,
                        const float* __restrict__ x, h16* __restrict__ x16,
                        h16* __restrict__ hi0) {
    const int T0 = 3 * 2 * 208 * 32, T = 3 * 7 * 208 * 32;
    const int TW = T0 + 3 * T;
    int idx = blockIdx.x * blockDim.x + threadIdx.x;
    if (idx >= TW) {
        int i = idx - TW;
        if (i < NN * FIN) { x16[i] = (h16)x[i]; return; }
        int i2 = i - NN * FIN;                 // hi0 pad cols [200,224)
        if (i2 < MP * 24) {
            int row = i2 / 24;
            hi0[(size_t)row * KPAD + 200 + (i2 - row * 24)] = (h16)0.f;
        }
        return;
    }
    const float* W; h16* o; int fin, ksteps, li;
    if (idx < T0) { W = W1; o = wt0; fin = FIN; ksteps = 2; li = idx; }
    else {
        int r = idx - T0; int l = r / T;
        li = r - l * T; fin = HD; ksteps = 7;
        W = (l == 0) ? W2 : ((l == 1) ? W3 : W4);
        o = (l == 0) ? wt1 : ((l == 1) ? wt2 : wt3);
    }
    int kk = li & 31;
    int r2 = li >> 5;
    int nn = r2 % 208;
    int r3 = r2 / 208;
    int ks = r3 % ksteps;
    int seg = r3 / ksteps;
    int k = ks * 32 + kk;
    float val = 0.f;
    if (nn < HD && k < fin) {
        size_t base = (size_t)k * HD + nn;
        size_t segsz = (size_t)fin * HD;
        if (seg == 0)      val = W[base] - W[2 * segsz + base];   // W0 - W2
        else if (seg == 1) val = W[segsz + base];                 // W1
        else               val = 2.f * W[2 * segsz + base];       // 2*W2
    }
    o[li] = (h16)val;
}

// ---------- propagation: XCD-pinned, line-aligned column slices, work-claiming ----------
// R1 post-mortem: gather is FETCH-bound at ~3.5 TB/s on the L2-miss path; 56-B slices
// straddled 64-B L2 lines -> per-XCD footprint 5.6 MB > 4 MB L2 -> thrash (FETCH 2x).
// Fix: ng=7 slices of 32 h16 = 64 B, exactly tiling the 448-B row, all line-aligned.
// Per-XCD slice footprint = MP*64B = 3.2 MB < 4 MB L2. Group chosen from the REAL
// XCD id (s_getreg HW_REG_XCC_ID, measured 0-7 on MI355X), g = xcc % ng; blocks claim
// 32-node chunks from per-group device counters and rotate to the next group when
// theirs drains (correct under ANY block->XCD mapping; XCD7 shares g0 then steals,
// giving ~7/8 makespan). csr (u32 {src:16,w:fp16}) + meta are nontemporal loads so
// the streams don't evict the pinned slice. v = gather + diag*hin (pure prop).
__global__ __launch_bounds__(256) void k_gather(
    const u64* __restrict__ meta, const unsigned* __restrict__ csr,
    const h16* __restrict__ hin16, h16* __restrict__ hout16,
    unsigned* __restrict__ ctr, int s16, int n, int ng, int nbTot) {
    unsigned xcc;
    asm volatile("s_getreg_b32 %0, hwreg(HW_REG_XCC_ID, 0, 4)" : "=s"(xcc));
    int g = (int)(xcc % (unsigned)ng);
    int tid = threadIdx.x;
    int sub = tid >> 3;                  // node slot 0..31 within claimed chunk
    int lane = tid & 7;                  // 8 lanes x uint2 = 64-B slice
    unsigned su = (unsigned)s16;
    __shared__ int snb;
    int tried = 0;
    union U { uint2 u; h16 h[4]; };
    union W16 { unsigned short u; h16 h; };
    for (;;) {
        if (tid == 0) snb = (int)atomicAdd(&ctr[g], 1u);
        __syncthreads();
        int nb = snb;
        __syncthreads();
        if (nb >= nbTot) {
            if (++tried >= ng) return;
            g = (g + 1 == ng) ? 0 : g + 1;
            continue;
        }
        int i = nb * 32 + sub;
        if (i < n) {
            unsigned c0 = (unsigned)(g * 32 + lane * 4);
            u64 m = __builtin_nontemporal_load(&meta[i]);
            int start = (int)(unsigned)(m & 0xffffffffu);
            int cnt = (int)((m >> 32) & 0xffffu);
            W16 dg16; dg16.u = (unsigned short)(m >> 48);
            float dg = (float)dg16.h;
            const unsigned* cp = csr + start;
            float g0 = 0.f, g1 = 0.f, g2 = 0.f, g3 = 0.f;
            int k = 0;
            for (; k + 7 < cnt; k += 8) {
                unsigned e[8];
#pragma unroll
                for (int j = 0; j < 8; ++j) e[j] = __builtin_nontemporal_load(&cp[k + j]);
                U p[8];
#pragma unroll
                for (int j = 0; j < 8; ++j)
                    p[j].u = *(const uint2*)(hin16 + (size_t)((e[j] & 0xffffu) * su + c0));
#pragma unroll
                for (int j = 0; j < 8; ++j) {
                    W16 wv; wv.u = (unsigned short)(e[j] >> 16);
                    float w = (float)wv.h;
                    g0 += w * (float)p[j].h[0];
                    g1 += w * (float)p[j].h[1];
                    g2 += w * (float)p[j].h[2];
                    g3 += w * (float)p[j].h[3];
                }
            }
            for (; k + 1 < cnt; k += 2) {
                unsigned e0 = __builtin_nontemporal_load(&cp[k]);
                unsigned e1 = __builtin_nontemporal_load(&cp[k + 1]);
                U p0, p1;
                p0.u = *(const uint2*)(hin16 + (size_t)((e0 & 0xffffu) * su + c0));
                p1.u = *(const uint2*)(hin16 + (size_t)((e1 & 0xffffu) * su + c0));
                W16 w0v, w1v; w0v.u = (unsigned short)(e0 >> 16); w1v.u = (unsigned short)(e1 >> 16);
                float w0 = (float)w0v.h, w1 = (float)w1v.h;
                g0 += w0 * (float)p0.h[0] + w1 * (float)p1.h[0];
                g1 += w0 * (float)p0.h[1] + w1 * (float)p1.h[1];
                g2 += w0 * (float)p0.h[2] + w1 * (float)p1.h[2];
                g3 += w0 * (float)p0.h[3] + w1 * (float)p1.h[3];
            }
            if (k < cnt) {
                unsigned e0 = __builtin_nontemporal_load(&cp[k]);
                U p0;
                p0.u = *(const uint2*)(hin16 + (size_t)((e0 & 0xffffu) * su + c0));
                W16 w0v; w0v.u = (unsigned short)(e0 >> 16);
                float w0 = (float)w0v.h;
                g0 += w0 * (float)p0.h[0];
                g1 += w0 * (float)p0.h[1];
                g2 += w0 * (float)p0.h[2];
                g3 += w0 * (float)p0.h[3];
            }
            U hs; hs.u = *(const uint2*)(hin16 + (size_t)((unsigned)i * su + c0));
            U o;
            o.h[0] = (h16)(g0 + dg * (float)hs.h[0]);
            o.h[1] = (h16)(g1 + dg * (float)hs.h[1]);
            o.h[2] = (h16)(g2 + dg * (float)hs.h[2]);
            o.h[3] = (h16)(g3 + dg * (float)hs.h[3]);
            *(uint2*)(hout16 + (size_t)((unsigned)i * su + c0)) = o.u;
        }
    }
}

// ---------- MFMA fp16 GEMM, barrier-free: out = relu([A0|A1|A2] @ W + b) ----------
__global__ __launch_bounds__(256) void k_gemm16(
    const h16* __restrict__ A0, const h16* __restrict__ A1, const h16* __restrict__ A2,
    int strideA, int ksteps,
    const h16* __restrict__ Wt, const float* __restrict__ bias,
    h16* __restrict__ out16, int n) {
    int tid = threadIdx.x;
    int wave = tid >> 6, lane = tid & 63;
    int nq = lane & 15, quad = lane >> 4;
    int row0 = (blockIdx.x * 4 + wave) * 32;
    const h16* Aseg[3] = {A0, A1, A2};

    float4v acc[2][NT];
#pragma unroll
    for (int r = 0; r < 2; r++)
#pragma unroll
        for (int t = 0; t < NT; t++) acc[r][t] = (float4v)0.f;

    for (int seg = 0; seg < 3; ++seg) {
        const h16* Ab = Aseg[seg] + (size_t)(row0 + nq) * strideA + quad * 8;
        const h16* Bb = Wt + (size_t)seg * ksteps * 208 * 32 + (size_t)nq * 32 + quad * 8;
        for (int ks = 0; ks < ksteps; ++ks) {
            half8 af0 = *(const half8*)(Ab + ks * 32);
            half8 af1 = *(const half8*)(Ab + 16 * strideA + ks * 32);
            const h16* Bk = Bb + (size_t)ks * 208 * 32;
#pragma unroll
            for (int t = 0; t < NT; ++t) {
                half8 bf = *(const half8*)(Bk + t * 16 * 32);
                acc[0][t] = __builtin_amdgcn_mfma_f32_16x16x32_f16(af0, bf, acc[0][t], 0, 0, 0);
                acc[1][t] = __builtin_amdgcn_mfma_f32_16x16x32_f16(af1, bf, acc[1][t], 0, 0, 0);
            }
        }
    }
#pragma unroll
    for (int r = 0; r < 2; ++r) {
        int rowb = row0 + r * 16 + quad * 4;
#pragma unroll
        for (int t = 0; t < NT; ++t) {
            int col = t * 16 + nq;
            if (col >= HD) continue;
            float bj = bias[col];
#pragma unroll
            for (int g = 0; g < 4; ++g) {
                int row = rowb + g;
                if (row < n)
                    out16[(size_t)row * KPAD + col] = (h16)fmaxf(acc[r][t][g] + bj, 0.0f);
            }
        }
    }
}

// ---------- fused segmented pool (mean+max) + FC + log_softmax (fp16 input) ----------
__global__ __launch_bounds__(256) void k_pool_fc(
    const h16* __restrict__ Hf, const int* __restrict__ gstart,
    const float* __restrict__ fcw, const float* __restrict__ fcb,
    float* __restrict__ out) {
    __shared__ float red[8];
    int g = blockIdx.x;
    int j = threadIdx.x;
    int i0 = gstart[g], i1 = gstart[g + 1];
    float s0 = 0.f, s1 = 0.f, s2 = 0.f, s3 = 0.f, mx = 0.f;   // post-ReLU: max >= 0
    if (j < HD) {
        int i = i0;
        for (; i + 3 < i1; i += 4) {
            float v0 = (float)Hf[(size_t)i * KPAD + j];
            float v1 = (float)Hf[(size_t)(i + 1) * KPAD + j];
            float v2 = (float)Hf[(size_t)(i + 2) * KPAD + j];
            float v3 = (float)Hf[(size_t)(i + 3) * KPAD + j];
            s0 += v0; s1 += v1; s2 += v2; s3 += v3;
            mx = fmaxf(mx, fmaxf(fmaxf(v0, v1), fmaxf(v2, v3)));
        }
        for (; i < i1; ++i) {
            float v = (float)Hf[(size_t)i * KPAD + j];
            s0 += v; mx = fmaxf(mx, v);
        }
    }
    float cntf = (float)(i1 - i0);
    float mean = (s0 + s1 + s2 + s3) / fmaxf(cntf, 1.f);
    float p0 = 0.f, p1 = 0.f;
    if (j < HD) {
        p0 = mean * fcw[2 * j]     + mx * fcw[2 * (HD + j)];
        p1 = mean * fcw[2 * j + 1] + mx * fcw[2 * (HD + j) + 1];
    }
#pragma unroll
    for (int o = 32; o > 0; o >>= 1) {
        p0 += __shfl_down(p0, o);
        p1 += __shfl_down(p1, o);
    }
    int wave = j >> 6, lane = j & 63;
    if (lane == 0) { red[wave * 2] = p0; red[wave * 2 + 1] = p1; }
    __syncthreads();
    if (j == 0) {
        float z0 = red[0] + red[2] + red[4] + red[6] + fcb[0];
        float z1 = red[1] + red[3] + red[5] + red[7] + fcb[1];
        float m = fmaxf(z0, z1);
        float lse = m + logf(expf(z0 - m) + expf(z1 - m));
        out[g * 2 + 0] = z0 - lse;
        out[g * 2 + 1] = z1 - lse;
    }
}

extern "C" void kernel_launch(void* const* d_in, const int* in_sizes, int n_in,
                              void* d_out, int out_size, void* d_ws, size_t ws_size,
                              hipStream_t stream) {
    const float* x     = (const float*)d_in[0];
    const int*   edge  = (const int*)d_in[1];
    const int*   batch = (const int*)d_in[2];
    const float* lmax  = (const float*)d_in[3];
    const float* W1 = (const float*)d_in[4];  const float* b1 = (const float*)d_in[5];
    const float* W2 = (const float*)d_in[6];  const float* b2 = (const float*)d_in[7];
    const float* W3 = (const float*)d_in[8];  const float* b3 = (const float*)d_in[9];
    const float* W4 = (const float*)d_in[10]; const float* b4 = (const float*)d_in[11];
    const float* fcw = (const float*)d_in[12]; const float* fcb = (const float*)d_in[13];
    float* out = (float*)d_out;

    const int n = NN, E = NE;
    const int* src = edge;
    const int* dst = edge + E;

    // workspace layout (float units, each buffer 16B-aligned)
    float* ws = (float*)d_ws;
    size_t off = 0;
    auto alloc = [&](size_t nfloats) { float* p = ws + off; off += (nfloats + 3) & ~(size_t)3; return p; };
    int*   degi   = (int*)alloc(NN);
    float* dis    = alloc(NN);
    float* qs     = alloc(NN);
    float* diag   = alloc(NN);
    int*   cntd   = (int*)alloc(NN);
    int*   excl   = (int*)alloc(NN);
    int*   bsum   = (int*)alloc(SCAN_B);
    unsigned* csr = (unsigned*)alloc(NE);                   // packed {src:16, w:fp16}
    u64*   meta   = (u64*)alloc((size_t)2 * NN);            // {start:32, cnt:16, diag:16}
    unsigned* ctr = (unsigned*)alloc(64);                   // 8 gather launches x 8 groups
    int*   gstart = (int*)alloc(NG + 1);
    unsigned* pSrc = (unsigned*)alloc((size_t)2 * 256 * HB);  // src histogram partials
    unsigned* pDst = (unsigned*)alloc((size_t)2 * 256 * HB);  // dst histogram partials/bases
    h16*   x16    = (h16*)alloc((size_t)MP * FIN / 2);      // fp16 x (stride 64)
    h16*   hi0    = (h16*)alloc((size_t)MP * KPAD / 2);     // fp16 h (inter-layer, in-place)
    h16*   hi1    = (h16*)alloc((size_t)MP * KPAD / 2);     // fp16 Tx1 / final features
    h16*   hi2    = (h16*)alloc((size_t)MP * KPAD / 2);     // fp16 P2 = prop(Tx1)
    const int WSZ0 = 3 * 2 * 208 * 32;
    const int WSZ  = 3 * 7 * 208 * 32;
    h16* wt0 = (h16*)alloc(WSZ0 / 2);
    h16* wt1 = (h16*)alloc(WSZ / 2);
    h16* wt2 = (h16*)alloc(WSZ / 2);
    h16* wt3 = (h16*)alloc(WSZ / 2);

    dim3 blk(256);
    int gN = (n + 255) / 256;
    int gScan = (n + SCAN_B - 1) / SCAN_B;      // 196
    int gGemm = MP / 128;                       // 391 blocks, 4 waves x 32 rows
    int gWp = (WSZ0 + 3 * WSZ + NN * FIN + MP * 24 + 255) / 256;

    // --- setup ---
    k_wprep<<<gWp, blk, 0, stream>>>(W1, W2, W3, W4, wt0, wt1, wt2, wt3, x, x16, hi0);
    k_hist<<<512, blk, 0, stream>>>(src, dst, pSrc, pDst, E);
    k_hredscan<<<(4 * HB + 255) / 256, blk, 0, stream>>>(pSrc, pDst, degi, cntd, n);
    k_prep<<<gN + 3, blk, 0, stream>>>(degi, batch, lmax, dis, qs, diag, gstart, ctr, n, gN);
    k_scan1<<<gScan, blk, 0, stream>>>(cntd, excl, bsum, n);
    k_scan2<<<1, blk, 0, stream>>>(bsum, gScan);
    k_meta<<<gScan, blk, 0, stream>>>(excl, bsum, cntd, diag, meta, n);
    k_fillcsr2<<<256, blk, 0, stream>>>(src, dst, qs, dis, excl, bsum, pDst, csr, E);

    // --- 4 Chebyshev layers (XCD-pinned sliced gathers + MFMA gemm) ---
    const h16* wt[4] = {wt0, wt1, wt2, wt3};
    const float* bl[4] = {b1, b2, b3, b4};
    int nbTot = (n + 31) / 32;                  // 1563 32-node chunks per group
    for (int l = 0; l < 4; l++) {
        int s16 = (l == 0) ? FIN : KPAD;
        int ng  = (l == 0) ? 2 : 7;             // 64-B line-aligned col slices
        int ksteps = (l == 0) ? 2 : 7;
        const h16* a0 = (l == 0) ? x16 : hi0;
        // Tx1 = prop(Tx0) -> hi1
        k_gather<<<2048, blk, 0, stream>>>(meta, csr, a0, hi1, ctr + (2 * l) * 8,
                                           s16, n, ng, nbTot);
        // P2 = prop(Tx1) -> hi2   (Chebyshev 2x / -Tx0 folded into weights)
        k_gather<<<2048, blk, 0, stream>>>(meta, csr, hi1, hi2, ctr + (2 * l + 1) * 8,
                                           s16, n, ng, nbTot);
        // out = relu(Tx0@(W0-W2) + Tx1@W1 + P2@(2W2) + b) -> hi0 (layers 0-2) or hi1 (final)
        k_gemm16<<<gGemm, blk, 0, stream>>>(a0, hi1, hi2, s16, ksteps, wt[l], bl[l],
                                            (l < 3) ? hi0 : hi1, n);
    }

    // --- fused pool + FC head (no atomics; batch is sorted; fp16 input) ---
    k_pool_fc<<<NG, blk, 0, stream>>>(hi1, gstart, fcw, fcb, out);
}

// Round 3
// 1247.018 us; speedup vs baseline: 1.9844x; 1.9844x over previous
//
#include <hip/hip_runtime.h>
#include <math.h>

#define NN 50000
#define MP 50048          // NN padded to multiple of 128 (32 rows x 4 waves)
#define NE 800000
#define FIN 64
#define HD 200
#define NG 256
#define SCAN_B 256
#define KPAD 224          // HD padded to multiple of 32 for MFMA K-steps
#define NT 13             // 13 * 16 = 208 >= 200 output col tiles
#define HB 12544          // LDS histogram packed dwords (covers 25088 nodes/pass)
#define PER_B 3125        // NE / 256 edges per histogram block

typedef _Float16 h16;
typedef __attribute__((ext_vector_type(8))) _Float16 half8;
typedef __attribute__((ext_vector_type(4))) float float4v;
typedef unsigned long long u64;

// ---------- dual histogram: blocks 0-255 src -> pSrc, 256-511 dst -> pDst ----------
__global__ __launch_bounds__(256) void k_hist(const int* __restrict__ src,
                                              const int* __restrict__ dst,
                                              unsigned* __restrict__ pSrc,
                                              unsigned* __restrict__ pDst, int E) {
    __shared__ unsigned h[HB];
    int tid = threadIdx.x;
    int isDst = blockIdx.x >> 8;
    int b = blockIdx.x & 255;
    const int* idx = isDst ? dst : src;
    unsigned* partial = isDst ? pDst : pSrc;
    int e0 = b * PER_B;
    int v[13];
#pragma unroll
    for (int j = 0; j < 13; ++j) {
        int o = j * 256 + tid;
        v[j] = (o < PER_B) ? idx[e0 + o] : -1;
    }
#pragma unroll
    for (int pass = 0; pass < 2; ++pass) {
        for (int t = tid; t < HB; t += 256) h[t] = 0;
        __syncthreads();
        int lo = pass * (2 * HB);
#pragma unroll
        for (int j = 0; j < 13; ++j) {
            int vv = v[j] - lo;
            if (vv >= 0 && vv < 2 * HB)
                atomicAdd(&h[vv >> 1], (vv & 1) ? 0x10000u : 1u);
        }
        __syncthreads();
        unsigned* pb = partial + ((size_t)pass * 256 + b) * HB;
        for (int t = tid; t < HB; t += 256) pb[t] = h[t];
        __syncthreads();
    }
}

// ---------- fused: reduce src partials -> degi ; scan dst partials -> bases + cntd ----------
__global__ void k_hredscan(const unsigned* __restrict__ pSrc, unsigned* __restrict__ pDst,
                           int* __restrict__ degi, int* __restrict__ cntd, int n) {
    int i = blockIdx.x * blockDim.x + threadIdx.x;
    if (i < 2 * HB) {
        int pass = i / HB, p = i - pass * HB;
        const unsigned* pb = pSrc + (size_t)pass * 256 * HB + p;
        unsigned s = 0;
        for (int b = 0; b < 256; ++b) s += pb[(size_t)b * HB];
        int n0 = pass * 2 * HB + 2 * p;
        if (n0 < n)     degi[n0]     = (int)(s & 0xffffu);
        if (n0 + 1 < n) degi[n0 + 1] = (int)(s >> 16);
    } else if (i < 4 * HB) {
        int j = i - 2 * HB;
        int pass = j / HB, p = j - pass * HB;
        unsigned* pb = pDst + (size_t)pass * 256 * HB + p;
        unsigned run = 0;
        for (int b = 0; b < 256; ++b) {
            unsigned c = pb[(size_t)b * HB];
            pb[(size_t)b * HB] = run;
            run += c;
        }
        int n0 = pass * 2 * HB + 2 * p;
        if (n0 < n)     cntd[n0]     = (int)(run & 0xffffu);
        if (n0 + 1 < n) cntd[n0 + 1] = (int)(run >> 16);
    }
}

// ---------- fused node prep (dis/qs/diag) + graph bounds ----------
__global__ void k_prep(const int* __restrict__ degi, const int* __restrict__ batch,
                       const float* __restrict__ lmax, float* __restrict__ dis,
                       float* __restrict__ qs, float* __restrict__ diag,
                       int* __restrict__ gstart, int n, int gN) {
    int b = blockIdx.x;
    if (b < gN) {
        int i = b * 256 + threadIdx.x;
        if (i < n) {
            int d = degi[i];
            float di = (d > 0) ? (1.0f / sqrtf((float)d)) : 0.0f;
            float sc = 2.0f / lmax[batch[i]];
            dis[i] = di;
            qs[i] = -di * sc;
            diag[i] = sc - 1.0f;
        }
    } else {
        int g = (b - gN) * 256 + threadIdx.x;
        if (g > NG) return;
        if (g == NG) { gstart[NG] = n; return; }
        int lo = 0, hi = n;
        while (lo < hi) {
            int mid = (lo + hi) >> 1;
            if (batch[mid] < g) lo = mid + 1; else hi = mid;
        }
        gstart[g] = lo;
    }
}

// ---------- exclusive scan over cnt_dst (block-local; global base added by consumers) ----------
__global__ void k_scan1(const int* __restrict__ cnt, int* __restrict__ excl,
                        int* __restrict__ bsum, int n) {
    __shared__ int sh[SCAN_B];
    int tid = threadIdx.x;
    int i = blockIdx.x * SCAN_B + tid;
    int v = (i < n) ? cnt[i] : 0;
    sh[tid] = v;
    __syncthreads();
    for (int off = 1; off < SCAN_B; off <<= 1) {
        int t = (tid >= off) ? sh[tid - off] : 0;
        __syncthreads();
        sh[tid] += t;
        __syncthreads();
    }
    if (i < n) excl[i] = sh[tid] - v;
    if (tid == SCAN_B - 1) bsum[blockIdx.x] = sh[tid];
}

__global__ void k_scan2(int* __restrict__ bsum, int nb) {
    __shared__ int sh[SCAN_B];
    int tid = threadIdx.x;
    int v = (tid < nb) ? bsum[tid] : 0;
    sh[tid] = v;
    __syncthreads();
    for (int off = 1; off < SCAN_B; off <<= 1) {
        int t = (tid >= off) ? sh[tid - off] : 0;
        __syncthreads();
        sh[tid] += t;
        __syncthreads();
    }
    if (tid < nb) bsum[tid] = sh[tid] - v;   // exclusive over block totals
}

// ---------- per-node meta: {rowstart:32, cnt:16, diag(fp16):16} packed u64 ----------
__global__ void k_meta(const int* __restrict__ excl, const int* __restrict__ bsum,
                       const int* __restrict__ cntd, const float* __restrict__ diag,
                       u64* __restrict__ meta, int n) {
    int i = blockIdx.x * 256 + threadIdx.x;
    if (i >= n) return;
    unsigned start = (unsigned)(excl[i] + bsum[i >> 8]);
    union { h16 h; unsigned short u; } d;
    d.h = (h16)diag[i];
    meta[i] = (u64)start | ((u64)(unsigned)cntd[i] << 32) | ((u64)d.u << 48);
}

// ---------- CSR fill, zero global atomics. Edge record = u32 {src:16, w:fp16:16} ----------
__global__ __launch_bounds__(256) void k_fillcsr2(
    const int* __restrict__ src, const int* __restrict__ dst,
    const float* __restrict__ qs, const float* __restrict__ dis,
    const int* __restrict__ excl, const int* __restrict__ bsum,
    const unsigned* __restrict__ hpart, unsigned* __restrict__ csr, int E) {
    __shared__ unsigned lrank[HB];
    int tid = threadIdx.x;
    int e0 = blockIdx.x * PER_B;
    int vs[13], vd[13];
#pragma unroll
    for (int j = 0; j < 13; ++j) {
        int o = j * 256 + tid;
        vs[j] = (o < PER_B) ? src[e0 + o] : -1;
        vd[j] = (o < PER_B) ? dst[e0 + o] : -1;
    }
#pragma unroll
    for (int pass = 0; pass < 2; ++pass) {
        for (int t = tid; t < HB; t += 256) lrank[t] = 0;
        __syncthreads();
        int lo = pass * (2 * HB);
        const unsigned* base = hpart + ((size_t)pass * 256 + blockIdx.x) * HB;
#pragma unroll
        for (int j = 0; j < 13; ++j) {
            int vv = vd[j] - lo;
            if (vv >= 0 && vv < 2 * HB) {
                unsigned old = atomicAdd(&lrank[vv >> 1], (vv & 1) ? 0x10000u : 1u);
                unsigned rank = (vv & 1) ? (old >> 16) : (old & 0xffffu);
                unsigned bs = base[vv >> 1];
                unsigned bb = (vv & 1) ? (bs >> 16) : (bs & 0xffffu);
                int s = vs[j], d = vd[j];
                int pos = excl[d] + bsum[d >> 8] + (int)bb + (int)rank;
                union { h16 h; unsigned short u; } cw;
                cw.h = (h16)(qs[s] * dis[d]);
                csr[pos] = (unsigned)s | ((unsigned)cw.u << 16);
            }
        }
        __syncthreads();
    }
}

// ---------- W pre-transpose (Chebyshev fold) + x fp32->fp16 + hi0 pad-col zeroing ----------
// out = Tx0*(W0-W2) + Tx1*W1 + prop(Tx1)*(2*W2): gathers are pure props.
// fp16 [seg][ks][208][32]; B k-pads ZERO; hi0 cols [200,224) zeroed once so layer-1
// gather input pads are finite (A-pad x B-zero stays zero in MFMA).
__global__ void k_wprep(const float* __restrict__ W1, const float* __restrict__ W2,
                        const float* __restrict__ W3, const float* __restrict__ W4,
                        h16* __restrict__ wt0, h16* __restrict__ wt1,
                        h16* __restrict__ wt2, h16* __restrict__ wt3,
                        const float* __restrict__ x, h16* __restrict__ x16,
                        h16* __restrict__ hi0) {
    const int T0 = 3 * 2 * 208 * 32, T = 3 * 7 * 208 * 32;
    const int TW = T0 + 3 * T;
    int idx = blockIdx.x * blockDim.x + threadIdx.x;
    if (idx >= TW) {
        int i = idx - TW;
        if (i < NN * FIN) { x16[i] = (h16)x[i]; return; }
        int i2 = i - NN * FIN;                 // hi0 pad cols [200,224)
        if (i2 < MP * 24) {
            int row = i2 / 24;
            hi0[(size_t)row * KPAD + 200 + (i2 - row * 24)] = (h16)0.f;
        }
        return;
    }
    const float* W; h16* o; int fin, ksteps, li;
    if (idx < T0) { W = W1; o = wt0; fin = FIN; ksteps = 2; li = idx; }
    else {
        int r = idx - T0; int l = r / T;
        li = r - l * T; fin = HD; ksteps = 7;
        W = (l == 0) ? W2 : ((l == 1) ? W3 : W4);
        o = (l == 0) ? wt1 : ((l == 1) ? wt2 : wt3);
    }
    int kk = li & 31;
    int r2 = li >> 5;
    int nn = r2 % 208;
    int r3 = r2 / 208;
    int ks = r3 % ksteps;
    int seg = r3 / ksteps;
    int k = ks * 32 + kk;
    float val = 0.f;
    if (nn < HD && k < fin) {
        size_t base = (size_t)k * HD + nn;
        size_t segsz = (size_t)fin * HD;
        if (seg == 0)      val = W[base] - W[2 * segsz + base];   // W0 - W2
        else if (seg == 1) val = W[segsz + base];                 // W1
        else               val = 2.f * W[2 * segsz + base];       // 2*W2
    }
    o[li] = (h16)val;
}

// ---------- propagation: statically XCD-pinned 64-B column slices ----------
// R2 post-mortem: the dynamic claim loop (device atomic + 2 barriers per chunk)
// serialized the kernel (VALUBusy 7.5%) and xcc%7 never pinned (FETCH full-miss).
// R3: pure static mapping. Row (448 B) = 7 line-aligned 64-B slices; group
// g = blockIdx & 7 -> XCD g under the round-robin blockIdx->XCD mapping (the
// measured basis of the T1 swizzle). Groups 0-6 cover the row; g==7 returns
// (XCD 7 idles: -1/8 peak, +bit-identical KPAD/GEMM/buffers vs the 780-us R0).
// Per-XCD slice footprint = MP*64B = 3.2 MB < 4 MB L2; csr/meta are nontemporal
// streams so they don't evict it. Blocks are uniform (32 nodes ~ 512 edges +-4.5%)
// so the mapping doesn't drift. Layer 0 (s16=64): 2 slices, g = blockIdx & 1.
// v = gather + diag*hin (pure prop; Chebyshev folded into weights).
__global__ __launch_bounds__(256) void k_gather(
    const u64* __restrict__ meta, const unsigned* __restrict__ csr,
    const h16* __restrict__ hin16, h16* __restrict__ hout16,
    int s16, int n, int gmask) {
    int g = blockIdx.x & gmask;
    if (g * 32 >= s16) return;               // pad group (g==7 at s16=224): idle
    int i = (blockIdx.x >> (gmask == 7 ? 3 : 1)) * 32 + (threadIdx.x >> 3);
    if (i >= n) return;
    int lane = threadIdx.x & 7;
    unsigned c0 = (unsigned)(g * 32 + lane * 4);
    unsigned su = (unsigned)s16;
    union U { uint2 u; h16 h[4]; };
    union W16 { unsigned short u; h16 h; };
    u64 m = __builtin_nontemporal_load(&meta[i]);
    int start = (int)(unsigned)(m & 0xffffffffu);
    int cnt = (int)((m >> 32) & 0xffffu);
    W16 dg16; dg16.u = (unsigned short)(m >> 48);
    float dg = (float)dg16.h;
    const unsigned* cp = csr + start;
    float g0 = 0.f, g1 = 0.f, g2 = 0.f, g3 = 0.f;
    int k = 0;
    for (; k + 7 < cnt; k += 8) {
        unsigned e[8];
#pragma unroll
        for (int j = 0; j < 8; ++j) e[j] = __builtin_nontemporal_load(&cp[k + j]);
        U p[8];
#pragma unroll
        for (int j = 0; j < 8; ++j)
            p[j].u = *(const uint2*)(hin16 + (size_t)((e[j] & 0xffffu) * su + c0));
#pragma unroll
        for (int j = 0; j < 8; ++j) {
            W16 wv; wv.u = (unsigned short)(e[j] >> 16);
            float w = (float)wv.h;
            g0 += w * (float)p[j].h[0];
            g1 += w * (float)p[j].h[1];
            g2 += w * (float)p[j].h[2];
            g3 += w * (float)p[j].h[3];
        }
    }
    for (; k + 1 < cnt; k += 2) {
        unsigned e0 = __builtin_nontemporal_load(&cp[k]);
        unsigned e1 = __builtin_nontemporal_load(&cp[k + 1]);
        U p0, p1;
        p0.u = *(const uint2*)(hin16 + (size_t)((e0 & 0xffffu) * su + c0));
        p1.u = *(const uint2*)(hin16 + (size_t)((e1 & 0xffffu) * su + c0));
        W16 w0v, w1v; w0v.u = (unsigned short)(e0 >> 16); w1v.u = (unsigned short)(e1 >> 16);
        float w0 = (float)w0v.h, w1 = (float)w1v.h;
        g0 += w0 * (float)p0.h[0] + w1 * (float)p1.h[0];
        g1 += w0 * (float)p0.h[1] + w1 * (float)p1.h[1];
        g2 += w0 * (float)p0.h[2] + w1 * (float)p1.h[2];
        g3 += w0 * (float)p0.h[3] + w1 * (float)p1.h[3];
    }
    if (k < cnt) {
        unsigned e0 = __builtin_nontemporal_load(&cp[k]);
        U p0;
        p0.u = *(const uint2*)(hin16 + (size_t)((e0 & 0xffffu) * su + c0));
        W16 w0v; w0v.u = (unsigned short)(e0 >> 16);
        float w0 = (float)w0v.h;
        g0 += w0 * (float)p0.h[0];
        g1 += w0 * (float)p0.h[1];
        g2 += w0 * (float)p0.h[2];
        g3 += w0 * (float)p0.h[3];
    }
    U hs; hs.u = *(const uint2*)(hin16 + (size_t)((unsigned)i * su + c0));
    U o;
    o.h[0] = (h16)(g0 + dg * (float)hs.h[0]);
    o.h[1] = (h16)(g1 + dg * (float)hs.h[1]);
    o.h[2] = (h16)(g2 + dg * (float)hs.h[2]);
    o.h[3] = (h16)(g3 + dg * (float)hs.h[3]);
    *(uint2*)(hout16 + (size_t)((unsigned)i * su + c0)) = o.u;
}

// ---------- MFMA fp16 GEMM, barrier-free: out = relu([A0|A1|A2] @ W + b) ----------
__global__ __launch_bounds__(256) void k_gemm16(
    const h16* __restrict__ A0, const h16* __restrict__ A1, const h16* __restrict__ A2,
    int strideA, int ksteps,
    const h16* __restrict__ Wt, const float* __restrict__ bias,
    h16* __restrict__ out16, int n) {
    int tid = threadIdx.x;
    int wave = tid >> 6, lane = tid & 63;
    int nq = lane & 15, quad = lane >> 4;
    int row0 = (blockIdx.x * 4 + wave) * 32;
    const h16* Aseg[3] = {A0, A1, A2};

    float4v acc[2][NT];
#pragma unroll
    for (int r = 0; r < 2; r++)
#pragma unroll
        for (int t = 0; t < NT; t++) acc[r][t] = (float4v)0.f;

    for (int seg = 0; seg < 3; ++seg) {
        const h16* Ab = Aseg[seg] + (size_t)(row0 + nq) * strideA + quad * 8;
        const h16* Bb = Wt + (size_t)seg * ksteps * 208 * 32 + (size_t)nq * 32 + quad * 8;
        for (int ks = 0; ks < ksteps; ++ks) {
            half8 af0 = *(const half8*)(Ab + ks * 32);
            half8 af1 = *(const half8*)(Ab + 16 * strideA + ks * 32);
            const h16* Bk = Bb + (size_t)ks * 208 * 32;
#pragma unroll
            for (int t = 0; t < NT; ++t) {
                half8 bf = *(const half8*)(Bk + t * 16 * 32);
                acc[0][t] = __builtin_amdgcn_mfma_f32_16x16x32_f16(af0, bf, acc[0][t], 0, 0, 0);
                acc[1][t] = __builtin_amdgcn_mfma_f32_16x16x32_f16(af1, bf, acc[1][t], 0, 0, 0);
            }
        }
    }
#pragma unroll
    for (int r = 0; r < 2; ++r) {
        int rowb = row0 + r * 16 + quad * 4;
#pragma unroll
        for (int t = 0; t < NT; ++t) {
            int col = t * 16 + nq;
            if (col >= HD) continue;
            float bj = bias[col];
#pragma unroll
            for (int g = 0; g < 4; ++g) {
                int row = rowb + g;
                if (row < n)
                    out16[(size_t)row * KPAD + col] = (h16)fmaxf(acc[r][t][g] + bj, 0.0f);
            }
        }
    }
}

// ---------- fused segmented pool (mean+max) + FC + log_softmax (fp16 input) ----------
__global__ __launch_bounds__(256) void k_pool_fc(
    const h16* __restrict__ Hf, const int* __restrict__ gstart,
    const float* __restrict__ fcw, const float* __restrict__ fcb,
    float* __restrict__ out) {
    __shared__ float red[8];
    int g = blockIdx.x;
    int j = threadIdx.x;
    int i0 = gstart[g], i1 = gstart[g + 1];
    float s0 = 0.f, s1 = 0.f, s2 = 0.f, s3 = 0.f, mx = 0.f;   // post-ReLU: max >= 0
    if (j < HD) {
        int i = i0;
        for (; i + 3 < i1; i += 4) {
            float v0 = (float)Hf[(size_t)i * KPAD + j];
            float v1 = (float)Hf[(size_t)(i + 1) * KPAD + j];
            float v2 = (float)Hf[(size_t)(i + 2) * KPAD + j];
            float v3 = (float)Hf[(size_t)(i + 3) * KPAD + j];
            s0 += v0; s1 += v1; s2 += v2; s3 += v3;
            mx = fmaxf(mx, fmaxf(fmaxf(v0, v1), fmaxf(v2, v3)));
        }
        for (; i < i1; ++i) {
            float v = (float)Hf[(size_t)i * KPAD + j];
            s0 += v; mx = fmaxf(mx, v);
        }
    }
    float cntf = (float)(i1 - i0);
    float mean = (s0 + s1 + s2 + s3) / fmaxf(cntf, 1.f);
    float p0 = 0.f, p1 = 0.f;
    if (j < HD) {
        p0 = mean * fcw[2 * j]     + mx * fcw[2 * (HD + j)];
        p1 = mean * fcw[2 * j + 1] + mx * fcw[2 * (HD + j) + 1];
    }
#pragma unroll
    for (int o = 32; o > 0; o >>= 1) {
        p0 += __shfl_down(p0, o);
        p1 += __shfl_down(p1, o);
    }
    int wave = j >> 6, lane = j & 63;
    if (lane == 0) { red[wave * 2] = p0; red[wave * 2 + 1] = p1; }
    __syncthreads();
    if (j == 0) {
        float z0 = red[0] + red[2] + red[4] + red[6] + fcb[0];
        float z1 = red[1] + red[3] + red[5] + red[7] + fcb[1];
        float m = fmaxf(z0, z1);
        float lse = m + logf(expf(z0 - m) + expf(z1 - m));
        out[g * 2 + 0] = z0 - lse;
        out[g * 2 + 1] = z1 - lse;
    }
}

extern "C" void kernel_launch(void* const* d_in, const int* in_sizes, int n_in,
                              void* d_out, int out_size, void* d_ws, size_t ws_size,
                              hipStream_t stream) {
    const float* x     = (const float*)d_in[0];
    const int*   edge  = (const int*)d_in[1];
    const int*   batch = (const int*)d_in[2];
    const float* lmax  = (const float*)d_in[3];
    const float* W1 = (const float*)d_in[4];  const float* b1 = (const float*)d_in[5];
    const float* W2 = (const float*)d_in[6];  const float* b2 = (const float*)d_in[7];
    const float* W3 = (const float*)d_in[8];  const float* b3 = (const float*)d_in[9];
    const float* W4 = (const float*)d_in[10]; const float* b4 = (const float*)d_in[11];
    const float* fcw = (const float*)d_in[12]; const float* fcb = (const float*)d_in[13];
    float* out = (float*)d_out;

    const int n = NN, E = NE;
    const int* src = edge;
    const int* dst = edge + E;

    // workspace layout (float units, each buffer 16B-aligned)
    float* ws = (float*)d_ws;
    size_t off = 0;
    auto alloc = [&](size_t nfloats) { float* p = ws + off; off += (nfloats + 3) & ~(size_t)3; return p; };
    int*   degi   = (int*)alloc(NN);
    float* dis    = alloc(NN);
    float* qs     = alloc(NN);
    float* diag   = alloc(NN);
    int*   cntd   = (int*)alloc(NN);
    int*   excl   = (int*)alloc(NN);
    int*   bsum   = (int*)alloc(SCAN_B);
    unsigned* csr = (unsigned*)alloc(NE);                   // packed {src:16, w:fp16}
    u64*   meta   = (u64*)alloc((size_t)2 * NN);            // {start:32, cnt:16, diag:16}
    int*   gstart = (int*)alloc(NG + 1);
    unsigned* pSrc = (unsigned*)alloc((size_t)2 * 256 * HB);  // src histogram partials
    unsigned* pDst = (unsigned*)alloc((size_t)2 * 256 * HB);  // dst histogram partials/bases
    h16*   x16    = (h16*)alloc((size_t)MP * FIN / 2);      // fp16 x (stride 64)
    h16*   hi0    = (h16*)alloc((size_t)MP * KPAD / 2);     // fp16 h (inter-layer, in-place)
    h16*   hi1    = (h16*)alloc((size_t)MP * KPAD / 2);     // fp16 Tx1 / final features
    h16*   hi2    = (h16*)alloc((size_t)MP * KPAD / 2);     // fp16 P2 = prop(Tx1)
    const int WSZ0 = 3 * 2 * 208 * 32;
    const int WSZ  = 3 * 7 * 208 * 32;
    h16* wt0 = (h16*)alloc(WSZ0 / 2);
    h16* wt1 = (h16*)alloc(WSZ / 2);
    h16* wt2 = (h16*)alloc(WSZ / 2);
    h16* wt3 = (h16*)alloc(WSZ / 2);

    dim3 blk(256);
    int gN = (n + 255) / 256;
    int gScan = (n + SCAN_B - 1) / SCAN_B;      // 196
    int gGemm = MP / 128;                       // 391 blocks, 4 waves x 32 rows
    int gWp = (WSZ0 + 3 * WSZ + NN * FIN + MP * 24 + 255) / 256;

    // --- setup ---
    k_wprep<<<gWp, blk, 0, stream>>>(W1, W2, W3, W4, wt0, wt1, wt2, wt3, x, x16, hi0);
    k_hist<<<512, blk, 0, stream>>>(src, dst, pSrc, pDst, E);
    k_hredscan<<<(4 * HB + 255) / 256, blk, 0, stream>>>(pSrc, pDst, degi, cntd, n);
    k_prep<<<gN + 2, blk, 0, stream>>>(degi, batch, lmax, dis, qs, diag, gstart, n, gN);
    k_scan1<<<gScan, blk, 0, stream>>>(cntd, excl, bsum, n);
    k_scan2<<<1, blk, 0, stream>>>(bsum, gScan);
    k_meta<<<gScan, blk, 0, stream>>>(excl, bsum, cntd, diag, meta, n);
    k_fillcsr2<<<256, blk, 0, stream>>>(src, dst, qs, dis, excl, bsum, pDst, csr, E);

    // --- 4 Chebyshev layers (statically XCD-pinned sliced gathers + MFMA gemm) ---
    const h16* wt[4] = {wt0, wt1, wt2, wt3};
    const float* bl[4] = {b1, b2, b3, b4};
    int nodeBlks = (n + 31) / 32;               // 1563 32-node chunks
    for (int l = 0; l < 4; l++) {
        int s16 = (l == 0) ? FIN : KPAD;
        int gmask = (l == 0) ? 1 : 7;           // 2 / 8 static col-groups
        int gGat = (gmask + 1) * nodeBlks;
        int ksteps = (l == 0) ? 2 : 7;
        const h16* a0 = (l == 0) ? x16 : hi0;
        // Tx1 = prop(Tx0) -> hi1
        k_gather<<<gGat, blk, 0, stream>>>(meta, csr, a0, hi1, s16, n, gmask);
        // P2 = prop(Tx1) -> hi2   (Chebyshev 2x / -Tx0 folded into weights)
        k_gather<<<gGat, blk, 0, stream>>>(meta, csr, hi1, hi2, s16, n, gmask);
        // out = relu(Tx0@(W0-W2) + Tx1@W1 + P2@(2W2) + b) -> hi0 (layers 0-2) or hi1 (final)
        k_gemm16<<<gGemm, blk, 0, stream>>>(a0, hi1, hi2, s16, ksteps, wt[l], bl[l],
                                            (l < 3) ? hi0 : hi1, n);
    }

    // --- fused pool + FC head (no atomics; batch is sorted; fp16 input) ---
    k_pool_fc<<<NG, blk, 0, stream>>>(hi1, gstart, fcw, fcb, out);
}

// Round 5
// 867.435 us; speedup vs baseline: 2.8527x; 1.4376x over previous
//
#include <hip/hip_runtime.h>
#include <math.h>

#define NN 50000
#define MP 50048          // NN padded to multiple of 128 (32 rows x 4 waves)
#define NE 800000
#define FIN 64
#define HD 200
#define NG 256
#define SCAN_B 256
#define KPAD 224          // HD padded to multiple of 32 for MFMA K-steps
#define NT 13             // 13 * 16 = 208 >= 200 output col tiles

typedef _Float16 h16;
typedef __attribute__((ext_vector_type(8))) _Float16 half8;
typedef __attribute__((ext_vector_type(4))) float float4v;
typedef unsigned long long u64;

// ---------- zero the atomic counter arrays (degi, cntd, fill) ----------
__global__ void k_zero(int* __restrict__ degi, int* __restrict__ cntd,
                       int* __restrict__ fill, int n) {
    int i = blockIdx.x * blockDim.x + threadIdx.x;
    if (i < n) { degi[i] = 0; cntd[i] = 0; fill[i] = 0; }
}

// ---------- degree + dst-count via direct global atomics (L2-resident counters) ----------
// Replaces the 512-block LDS histogram + 154-MB hredscan pipeline (~100 us of
// setup traffic -> ~20 us). 800k u32 atomics over 50k counters: trivial for L2.
__global__ __launch_bounds__(256) void k_degcnt(const int* __restrict__ src,
                                                const int* __restrict__ dst,
                                                int* __restrict__ degi,
                                                int* __restrict__ cntd, int E) {
    int i = blockIdx.x * blockDim.x + threadIdx.x;
    if (i >= E) return;
    atomicAdd(&degi[src[i]], 1);
    atomicAdd(&cntd[dst[i]], 1);
}

// ---------- fused node prep (dis/qs/diag) + graph bounds ----------
__global__ void k_prep(const int* __restrict__ degi, const int* __restrict__ batch,
                       const float* __restrict__ lmax, float* __restrict__ dis,
                       float* __restrict__ qs, float* __restrict__ diag,
                       int* __restrict__ gstart, int n, int gN) {
    int b = blockIdx.x;
    if (b < gN) {
        int i = b * 256 + threadIdx.x;
        if (i < n) {
            int d = degi[i];
            float di = (d > 0) ? (1.0f / sqrtf((float)d)) : 0.0f;
            float sc = 2.0f / lmax[batch[i]];
            dis[i] = di;
            qs[i] = -di * sc;
            diag[i] = sc - 1.0f;
        }
    } else {
        int g = (b - gN) * 256 + threadIdx.x;
        if (g > NG) return;
        if (g == NG) { gstart[NG] = n; return; }
        int lo = 0, hi = n;
        while (lo < hi) {
            int mid = (lo + hi) >> 1;
            if (batch[mid] < g) lo = mid + 1; else hi = mid;
        }
        gstart[g] = lo;
    }
}

// ---------- exclusive scan over cnt_dst (block-local; global base added by consumers) ----------
__global__ void k_scan1(const int* __restrict__ cnt, int* __restrict__ excl,
                        int* __restrict__ bsum, int n) {
    __shared__ int sh[SCAN_B];
    int tid = threadIdx.x;
    int i = blockIdx.x * SCAN_B + tid;
    int v = (i < n) ? cnt[i] : 0;
    sh[tid] = v;
    __syncthreads();
    for (int off = 1; off < SCAN_B; off <<= 1) {
        int t = (tid >= off) ? sh[tid - off] : 0;
        __syncthreads();
        sh[tid] += t;
        __syncthreads();
    }
    if (i < n) excl[i] = sh[tid] - v;
    if (tid == SCAN_B - 1) bsum[blockIdx.x] = sh[tid];
}

__global__ void k_scan2(int* __restrict__ bsum, int nb) {
    __shared__ int sh[SCAN_B];
    int tid = threadIdx.x;
    int v = (tid < nb) ? bsum[tid] : 0;
    sh[tid] = v;
    __syncthreads();
    for (int off = 1; off < SCAN_B; off <<= 1) {
        int t = (tid >= off) ? sh[tid - off] : 0;
        __syncthreads();
        sh[tid] += t;
        __syncthreads();
    }
    if (tid < nb) bsum[tid] = sh[tid] - v;   // exclusive over block totals
}

// ---------- per-node meta: {rowstart:32, cnt:16, diag(fp16):16} packed u64 ----------
__global__ void k_meta(const int* __restrict__ excl, const int* __restrict__ bsum,
                       const int* __restrict__ cntd, const float* __restrict__ diag,
                       u64* __restrict__ meta, int n) {
    int i = blockIdx.x * 256 + threadIdx.x;
    if (i >= n) return;
    unsigned start = (unsigned)(excl[i] + bsum[i >> 8]);
    union { h16 h; unsigned short u; } d;
    d.h = (h16)diag[i];
    meta[i] = (u64)start | ((u64)(unsigned)cntd[i] << 32) | ((u64)d.u << 48);
}

// ---------- CSR fill via atomic rank. Edge record = u32 {src:16, w:fp16:16} ----------
// Intra-row edge order is nondeterministic; the gather accumulates in fp32 over
// ~16 terms so the sum-order wiggle is ~1e-7 rel (tolerance is 7.8e-3).
__global__ __launch_bounds__(256) void k_fill(
    const int* __restrict__ src, const int* __restrict__ dst,
    const float* __restrict__ qs, const float* __restrict__ dis,
    const int* __restrict__ excl, const int* __restrict__ bsum,
    int* __restrict__ fill, unsigned* __restrict__ csr, int E) {
    int i = blockIdx.x * blockDim.x + threadIdx.x;
    if (i >= E) return;
    int s = src[i], d = dst[i];
    int r = atomicAdd(&fill[d], 1);
    int pos = excl[d] + bsum[d >> 8] + r;
    union { h16 h; unsigned short u; } cw;
    cw.h = (h16)(qs[s] * dis[d]);
    csr[pos] = (unsigned)s | ((unsigned)cw.u << 16);
}

// ---------- W pre-transpose (Chebyshev fold) + x fp32->fp16 + hi0 pad-col zeroing ----------
// out = Tx0*(W0-W2) + Tx1*W1 + prop(Tx1)*(2*W2): gathers are pure props.
// fp16 [seg][ks][208][32]; B k-pads ZERO; hi0 cols [200,224) zeroed once so layer-1
// gather input pads are finite (A-pad x B-zero stays zero in MFMA).
__global__ void k_wprep(const float* __restrict__ W1, const float* __restrict__ W2,
                        const float* __restrict__ W3, const float* __restrict__ W4,
                        h16* __restrict__ wt0, h16* __restrict__ wt1,
                        h16* __restrict__ wt2, h16* __restrict__ wt3,
                        const float* __restrict__ x, h16* __restrict__ x16,
                        h16* __restrict__ hi0) {
    const int T0 = 3 * 2 * 208 * 32, T = 3 * 7 * 208 * 32;
    const int TW = T0 + 3 * T;
    int idx = blockIdx.x * blockDim.x + threadIdx.x;
    if (idx >= TW) {
        int i = idx - TW;
        if (i < NN * FIN) { x16[i] = (h16)x[i]; return; }
        int i2 = i - NN * FIN;                 // hi0 pad cols [200,224)
        if (i2 < MP * 24) {
            int row = i2 / 24;
            hi0[(size_t)row * KPAD + 200 + (i2 - row * 24)] = (h16)0.f;
        }
        return;
    }
    const float* W; h16* o; int fin, ksteps, li;
    if (idx < T0) { W = W1; o = wt0; fin = FIN; ksteps = 2; li = idx; }
    else {
        int r = idx - T0; int l = r / T;
        li = r - l * T; fin = HD; ksteps = 7;
        W = (l == 0) ? W2 : ((l == 1) ? W3 : W4);
        o = (l == 0) ? wt1 : ((l == 1) ? wt2 : wt3);
    }
    int kk = li & 31;
    int r2 = li >> 5;
    int nn = r2 % 208;
    int r3 = r2 / 208;
    int ks = r3 % ksteps;
    int seg = r3 / ksteps;
    int k = ks * 32 + kk;
    float val = 0.f;
    if (nn < HD && k < fin) {
        size_t base = (size_t)k * HD + nn;
        size_t segsz = (size_t)fin * HD;
        if (seg == 0)      val = W[base] - W[2 * segsz + base];   // W0 - W2
        else if (seg == 1) val = W[segsz + base];                 // W1
        else               val = 2.f * W[2 * segsz + base];       // 2*W2
    }
    o[li] = (h16)val;
}

// ---------- propagation: R0's proven structure + verified byte trims ----------
// R1-R3 established: the gather is fetch-byte-bound at ~3.2-3.6 TB/s on the
// L2-miss path under ANY config; XCD slicing never pins (FETCH = full-miss
// model, 3/3 rounds). So: exact R0 loop (wave-per-node lsh=6 heavy / 16-lane
// groups lsh=4 light, 8-deep pipeline, oversubscribed grid) with the only
// levers that survive = fewer bytes: u32 csr ({src:16,w:fp16}, halves csr
// stream), packed meta (1 load replaces 4), weight-fold (no mode-1 h0 stream).
// csr/meta nontemporal: streams must not evict the row cache.
__global__ __launch_bounds__(256) void k_gather(
    const u64* __restrict__ meta, const unsigned* __restrict__ csr,
    const h16* __restrict__ hin16, h16* __restrict__ hout16,
    int s16, int lsh, int n) {
    int per = 256 >> lsh;
    int i = blockIdx.x * per + (threadIdx.x >> lsh);
    if (i >= n) return;
    int lane = threadIdx.x & ((1 << lsh) - 1);
    int c0 = lane * 4;
    if (c0 >= s16) return;                    // lsh=6, s16=224: lanes 56-63 idle
    unsigned su = (unsigned)s16;
    union U { uint2 u; h16 h[4]; };
    union W16 { unsigned short u; h16 h; };
    u64 m = __builtin_nontemporal_load(&meta[i]);
    int start = (int)(unsigned)(m & 0xffffffffu);
    int cnt = (int)((m >> 32) & 0xffffu);
    W16 dg16; dg16.u = (unsigned short)(m >> 48);
    float dg = (float)dg16.h;
    const unsigned* cp = csr + start;
    float g0 = 0.f, g1 = 0.f, g2 = 0.f, g3 = 0.f;
    int k = 0;
    for (; k + 7 < cnt; k += 8) {
        unsigned e[8];
#pragma unroll
        for (int j = 0; j < 8; ++j) e[j] = __builtin_nontemporal_load(&cp[k + j]);
        U p[8];
#pragma unroll
        for (int j = 0; j < 8; ++j)                              // 8 rows in flight
            p[j].u = *(const uint2*)(hin16 + (size_t)((e[j] & 0xffffu) * su + (unsigned)c0));
#pragma unroll
        for (int j = 0; j < 8; ++j) {
            W16 wv; wv.u = (unsigned short)(e[j] >> 16);
            float w = (float)wv.h;
            g0 += w * (float)p[j].h[0];
            g1 += w * (float)p[j].h[1];
            g2 += w * (float)p[j].h[2];
            g3 += w * (float)p[j].h[3];
        }
    }
    for (; k + 1 < cnt; k += 2) {
        unsigned e0 = __builtin_nontemporal_load(&cp[k]);
        unsigned e1 = __builtin_nontemporal_load(&cp[k + 1]);
        U p0, p1;
        p0.u = *(const uint2*)(hin16 + (size_t)((e0 & 0xffffu) * su + (unsigned)c0));
        p1.u = *(const uint2*)(hin16 + (size_t)((e1 & 0xffffu) * su + (unsigned)c0));
        W16 w0v, w1v; w0v.u = (unsigned short)(e0 >> 16); w1v.u = (unsigned short)(e1 >> 16);
        float w0 = (float)w0v.h, w1 = (float)w1v.h;
        g0 += w0 * (float)p0.h[0] + w1 * (float)p1.h[0];
        g1 += w0 * (float)p0.h[1] + w1 * (float)p1.h[1];
        g2 += w0 * (float)p0.h[2] + w1 * (float)p1.h[2];
        g3 += w0 * (float)p0.h[3] + w1 * (float)p1.h[3];
    }
    if (k < cnt) {
        unsigned e0 = __builtin_nontemporal_load(&cp[k]);
        U p0;
        p0.u = *(const uint2*)(hin16 + (size_t)((e0 & 0xffffu) * su + (unsigned)c0));
        W16 w0v; w0v.u = (unsigned short)(e0 >> 16);
        float w0 = (float)w0v.h;
        g0 += w0 * (float)p0.h[0];
        g1 += w0 * (float)p0.h[1];
        g2 += w0 * (float)p0.h[2];
        g3 += w0 * (float)p0.h[3];
    }
    U hs; hs.u = *(const uint2*)(hin16 + (size_t)((unsigned)i * su + (unsigned)c0));
    U o;
    o.h[0] = (h16)(g0 + dg * (float)hs.h[0]);
    o.h[1] = (h16)(g1 + dg * (float)hs.h[1]);
    o.h[2] = (h16)(g2 + dg * (float)hs.h[2]);
    o.h[3] = (h16)(g3 + dg * (float)hs.h[3]);
    *(uint2*)(hout16 + (size_t)((unsigned)i * su + (unsigned)c0)) = o.u;
}

// ---------- MFMA fp16 GEMM, barrier-free: out = relu([A0|A1|A2] @ W + b) ----------
// Each wave: 32 rows x 208 cols. In-place out16 over an A-buffer is safe:
// each row is read only by the wave that writes it, reads precede epilogue.
__global__ __launch_bounds__(256) void k_gemm16(
    const h16* __restrict__ A0, const h16* __restrict__ A1, const h16* __restrict__ A2,
    int strideA, int ksteps,
    const h16* __restrict__ Wt, const float* __restrict__ bias,
    h16* __restrict__ out16, int n) {
    int tid = threadIdx.x;
    int wave = tid >> 6, lane = tid & 63;
    int nq = lane & 15, quad = lane >> 4;
    int row0 = (blockIdx.x * 4 + wave) * 32;
    const h16* Aseg[3] = {A0, A1, A2};

    float4v acc[2][NT];
#pragma unroll
    for (int r = 0; r < 2; r++)
#pragma unroll
        for (int t = 0; t < NT; t++) acc[r][t] = (float4v)0.f;

    for (int seg = 0; seg < 3; ++seg) {
        const h16* Ab = Aseg[seg] + (size_t)(row0 + nq) * strideA + quad * 8;
        const h16* Bb = Wt + (size_t)seg * ksteps * 208 * 32 + (size_t)nq * 32 + quad * 8;
        for (int ks = 0; ks < ksteps; ++ks) {
            half8 af0 = *(const half8*)(Ab + ks * 32);
            half8 af1 = *(const half8*)(Ab + 16 * strideA + ks * 32);
            const h16* Bk = Bb + (size_t)ks * 208 * 32;
#pragma unroll
            for (int t = 0; t < NT; ++t) {
                half8 bf = *(const half8*)(Bk + t * 16 * 32);
                acc[0][t] = __builtin_amdgcn_mfma_f32_16x16x32_f16(af0, bf, acc[0][t], 0, 0, 0);
                acc[1][t] = __builtin_amdgcn_mfma_f32_16x16x32_f16(af1, bf, acc[1][t], 0, 0, 0);
            }
        }
    }
#pragma unroll
    for (int r = 0; r < 2; ++r) {
        int rowb = row0 + r * 16 + quad * 4;
#pragma unroll
        for (int t = 0; t < NT; ++t) {
            int col = t * 16 + nq;
            if (col >= HD) continue;
            float bj = bias[col];
#pragma unroll
            for (int g = 0; g < 4; ++g) {
                int row = rowb + g;
                if (row < n)
                    out16[(size_t)row * KPAD + col] = (h16)fmaxf(acc[r][t][g] + bj, 0.0f);
            }
        }
    }
}

// ---------- fused segmented pool (mean+max) + FC + log_softmax (fp16 input) ----------
__global__ __launch_bounds__(256) void k_pool_fc(
    const h16* __restrict__ Hf, const int* __restrict__ gstart,
    const float* __restrict__ fcw, const float* __restrict__ fcb,
    float* __restrict__ out) {
    __shared__ float red[8];
    int g = blockIdx.x;
    int j = threadIdx.x;
    int i0 = gstart[g], i1 = gstart[g + 1];
    float s0 = 0.f, s1 = 0.f, s2 = 0.f, s3 = 0.f, mx = 0.f;   // post-ReLU: max >= 0
    if (j < HD) {
        int i = i0;
        for (; i + 3 < i1; i += 4) {
            float v0 = (float)Hf[(size_t)i * KPAD + j];
            float v1 = (float)Hf[(size_t)(i + 1) * KPAD + j];
            float v2 = (float)Hf[(size_t)(i + 2) * KPAD + j];
            float v3 = (float)Hf[(size_t)(i + 3) * KPAD + j];
            s0 += v0; s1 += v1; s2 += v2; s3 += v3;
            mx = fmaxf(mx, fmaxf(fmaxf(v0, v1), fmaxf(v2, v3)));
        }
        for (; i < i1; ++i) {
            float v = (float)Hf[(size_t)i * KPAD + j];
            s0 += v; mx = fmaxf(mx, v);
        }
    }
    float cntf = (float)(i1 - i0);
    float mean = (s0 + s1 + s2 + s3) / fmaxf(cntf, 1.f);
    float p0 = 0.f, p1 = 0.f;
    if (j < HD) {
        p0 = mean * fcw[2 * j]     + mx * fcw[2 * (HD + j)];
        p1 = mean * fcw[2 * j + 1] + mx * fcw[2 * (HD + j) + 1];
    }
#pragma unroll
    for (int o = 32; o > 0; o >>= 1) {
        p0 += __shfl_down(p0, o);
        p1 += __shfl_down(p1, o);
    }
    int wave = j >> 6, lane = j & 63;
    if (lane == 0) { red[wave * 2] = p0; red[wave * 2 + 1] = p1; }
    __syncthreads();
    if (j == 0) {
        float z0 = red[0] + red[2] + red[4] + red[6] + fcb[0];
        float z1 = red[1] + red[3] + red[5] + red[7] + fcb[1];
        float m = fmaxf(z0, z1);
        float lse = m + logf(expf(z0 - m) + expf(z1 - m));
        out[g * 2 + 0] = z0 - lse;
        out[g * 2 + 1] = z1 - lse;
    }
}

extern "C" void kernel_launch(void* const* d_in, const int* in_sizes, int n_in,
                              void* d_out, int out_size, void* d_ws, size_t ws_size,
                              hipStream_t stream) {
    const float* x     = (const float*)d_in[0];
    const int*   edge  = (const int*)d_in[1];
    const int*   batch = (const int*)d_in[2];
    const float* lmax  = (const float*)d_in[3];
    const float* W1 = (const float*)d_in[4];  const float* b1 = (const float*)d_in[5];
    const float* W2 = (const float*)d_in[6];  const float* b2 = (const float*)d_in[7];
    const float* W3 = (const float*)d_in[8];  const float* b3 = (const float*)d_in[9];
    const float* W4 = (const float*)d_in[10]; const float* b4 = (const float*)d_in[11];
    const float* fcw = (const float*)d_in[12]; const float* fcb = (const float*)d_in[13];
    float* out = (float*)d_out;

    const int n = NN, E = NE;
    const int* src = edge;
    const int* dst = edge + E;

    // workspace layout (float units, each buffer 16B-aligned)
    float* ws = (float*)d_ws;
    size_t off = 0;
    auto alloc = [&](size_t nfloats) { float* p = ws + off; off += (nfloats + 3) & ~(size_t)3; return p; };
    int*   degi   = (int*)alloc(NN);
    float* dis    = alloc(NN);
    float* qs     = alloc(NN);
    float* diag   = alloc(NN);
    int*   cntd   = (int*)alloc(NN);
    int*   excl   = (int*)alloc(NN);
    int*   fill   = (int*)alloc(NN);
    int*   bsum   = (int*)alloc(SCAN_B);
    unsigned* csr = (unsigned*)alloc(NE);                   // packed {src:16, w:fp16}
    u64*   meta   = (u64*)alloc((size_t)2 * NN);            // {start:32, cnt:16, diag:16}
    int*   gstart = (int*)alloc(NG + 1);
    h16*   x16    = (h16*)alloc((size_t)MP * FIN / 2);      // fp16 x (stride 64)
    h16*   hi0    = (h16*)alloc((size_t)MP * KPAD / 2);     // fp16 h (inter-layer, in-place)
    h16*   hi1    = (h16*)alloc((size_t)MP * KPAD / 2);     // fp16 Tx1 / final features
    h16*   hi2    = (h16*)alloc((size_t)MP * KPAD / 2);     // fp16 P2 = prop(Tx1)
    const int WSZ0 = 3 * 2 * 208 * 32;
    const int WSZ  = 3 * 7 * 208 * 32;
    h16* wt0 = (h16*)alloc(WSZ0 / 2);
    h16* wt1 = (h16*)alloc(WSZ / 2);
    h16* wt2 = (h16*)alloc(WSZ / 2);
    h16* wt3 = (h16*)alloc(WSZ / 2);

    dim3 blk(256);
    int gN = (n + 255) / 256;
    int gScan = (n + SCAN_B - 1) / SCAN_B;      // 196
    int gGemm = MP / 128;                       // 391 blocks, 4 waves x 32 rows
    int gE = (E + 255) / 256;                   // 3125
    int gWp = (WSZ0 + 3 * WSZ + NN * FIN + MP * 24 + 255) / 256;

    // --- setup (direct-atomic CSR build; ~20 us vs ~100 us histogram pipeline) ---
    k_wprep<<<gWp, blk, 0, stream>>>(W1, W2, W3, W4, wt0, wt1, wt2, wt3, x, x16, hi0);
    k_zero<<<gN, blk, 0, stream>>>(degi, cntd, fill, n);
    k_degcnt<<<gE, blk, 0, stream>>>(src, dst, degi, cntd, E);
    k_prep<<<gN + 2, blk, 0, stream>>>(degi, batch, lmax, dis, qs, diag, gstart, n, gN);
    k_scan1<<<gScan, blk, 0, stream>>>(cntd, excl, bsum, n);
    k_scan2<<<1, blk, 0, stream>>>(bsum, gScan);
    k_meta<<<gScan, blk, 0, stream>>>(excl, bsum, cntd, diag, meta, n);
    k_fill<<<gE, blk, 0, stream>>>(src, dst, qs, dis, excl, bsum, fill, csr, E);

    // --- 4 Chebyshev layers (R0-structure gathers + MFMA gemm) ---
    const h16* wt[4] = {wt0, wt1, wt2, wt3};
    const float* bl[4] = {b1, b2, b3, b4};
    for (int l = 0; l < 4; l++) {
        int s16 = (l == 0) ? FIN : KPAD;
        int lsh = (l == 0) ? 4 : 6;              // 16-lane groups (l0) / full wave
        int per = 256 >> lsh;
        int gGat = (n + per - 1) / per;
        int ksteps = (l == 0) ? 2 : 7;
        const h16* a0 = (l == 0) ? x16 : hi0;
        // Tx1 = prop(Tx0) -> hi1
        k_gather<<<gGat, blk, 0, stream>>>(meta, csr, a0, hi1, s16, lsh, n);
        // P2 = prop(Tx1) -> hi2   (Chebyshev 2x / -Tx0 folded into weights)
        k_gather<<<gGat, blk, 0, stream>>>(meta, csr, hi1, hi2, s16, lsh, n);
        // out = relu(Tx0@(W0-W2) + Tx1@W1 + P2@(2W2) + b) -> hi0 (layers 0-2) or hi1 (final)
        k_gemm16<<<gGemm, blk, 0, stream>>>(a0, hi1, hi2, s16, ksteps, wt[l], bl[l],
                                            (l < 3) ? hi0 : hi1, n);
    }

    // --- fused pool + FC head (no atomics; batch is sorted; fp16 input) ---
    k_pool_fc<<<NG, blk, 0, stream>>>(hi1, gstart, fcw, fcb, out);
}

// Round 6
// 775.021 us; speedup vs baseline: 3.1929x; 1.1192x over previous
//
#include <hip/hip_runtime.h>
#include <math.h>

#define NN 50000
#define MP 50048          // NN padded to multiple of 128 (32 rows x 4 waves)
#define NE 800000
#define FIN 64
#define HD 200
#define NG 256
#define SCAN_B 256
#define KPAD 224          // HD padded to multiple of 32 for MFMA K-steps
#define NT 13             // 13 * 16 = 208 >= 200 output col tiles
#define HB 12544          // LDS histogram packed dwords (covers 25088 nodes/pass)
#define PER_B 3125        // NE / 256 edges per histogram block

typedef _Float16 h16;
typedef __attribute__((ext_vector_type(8))) _Float16 half8;
typedef __attribute__((ext_vector_type(4))) float float4v;
typedef unsigned long long u64;

// ---------- dual histogram: blocks 0-255 src -> pSrc, 256-511 dst -> pDst ----------
// R5 lesson: device-scope atomic-with-return chains cost 72.7 us (k_fill) at
// VALUBusy 0.6% -- the LDS-histogram pipeline exists to avoid exactly that.
__global__ __launch_bounds__(256) void k_hist(const int* __restrict__ src,
                                              const int* __restrict__ dst,
                                              unsigned* __restrict__ pSrc,
                                              unsigned* __restrict__ pDst, int E) {
    __shared__ unsigned h[HB];
    int tid = threadIdx.x;
    int isDst = blockIdx.x >> 8;
    int b = blockIdx.x & 255;
    const int* idx = isDst ? dst : src;
    unsigned* partial = isDst ? pDst : pSrc;
    int e0 = b * PER_B;
    int v[13];
#pragma unroll
    for (int j = 0; j < 13; ++j) {
        int o = j * 256 + tid;
        v[j] = (o < PER_B) ? idx[e0 + o] : -1;
    }
#pragma unroll
    for (int pass = 0; pass < 2; ++pass) {
        for (int t = tid; t < HB; t += 256) h[t] = 0;
        __syncthreads();
        int lo = pass * (2 * HB);
#pragma unroll
        for (int j = 0; j < 13; ++j) {
            int vv = v[j] - lo;
            if (vv >= 0 && vv < 2 * HB)
                atomicAdd(&h[vv >> 1], (vv & 1) ? 0x10000u : 1u);
        }
        __syncthreads();
        unsigned* pb = partial + ((size_t)pass * 256 + b) * HB;
        for (int t = tid; t < HB; t += 256) pb[t] = h[t];
        __syncthreads();
    }
}

// ---------- fused: reduce src partials -> degi ; scan dst partials -> bases + cntd ----------
__global__ void k_hredscan(const unsigned* __restrict__ pSrc, unsigned* __restrict__ pDst,
                           int* __restrict__ degi, int* __restrict__ cntd, int n) {
    int i = blockIdx.x * blockDim.x + threadIdx.x;
    if (i < 2 * HB) {
        int pass = i / HB, p = i - pass * HB;
        const unsigned* pb = pSrc + (size_t)pass * 256 * HB + p;
        unsigned s = 0;
        for (int b = 0; b < 256; ++b) s += pb[(size_t)b * HB];
        int n0 = pass * 2 * HB + 2 * p;
        if (n0 < n)     degi[n0]     = (int)(s & 0xffffu);
        if (n0 + 1 < n) degi[n0 + 1] = (int)(s >> 16);
    } else if (i < 4 * HB) {
        int j = i - 2 * HB;
        int pass = j / HB, p = j - pass * HB;
        unsigned* pb = pDst + (size_t)pass * 256 * HB + p;
        unsigned run = 0;
        for (int b = 0; b < 256; ++b) {
            unsigned c = pb[(size_t)b * HB];
            pb[(size_t)b * HB] = run;
            run += c;
        }
        int n0 = pass * 2 * HB + 2 * p;
        if (n0 < n)     cntd[n0]     = (int)(run & 0xffffu);
        if (n0 + 1 < n) cntd[n0 + 1] = (int)(run >> 16);
    }
}

// ---------- fused node prep (dis/qs/diag) + graph bounds ----------
__global__ void k_prep(const int* __restrict__ degi, const int* __restrict__ batch,
                       const float* __restrict__ lmax, float* __restrict__ dis,
                       float* __restrict__ qs, float* __restrict__ diag,
                       int* __restrict__ gstart, int n, int gN) {
    int b = blockIdx.x;
    if (b < gN) {
        int i = b * 256 + threadIdx.x;
        if (i < n) {
            int d = degi[i];
            float di = (d > 0) ? (1.0f / sqrtf((float)d)) : 0.0f;
            float sc = 2.0f / lmax[batch[i]];
            dis[i] = di;
            qs[i] = -di * sc;
            diag[i] = sc - 1.0f;
        }
    } else {
        int g = (b - gN) * 256 + threadIdx.x;
        if (g > NG) return;
        if (g == NG) { gstart[NG] = n; return; }
        int lo = 0, hi = n;
        while (lo < hi) {
            int mid = (lo + hi) >> 1;
            if (batch[mid] < g) lo = mid + 1; else hi = mid;
        }
        gstart[g] = lo;
    }
}

// ---------- exclusive scan over cnt_dst (block-local; global base added by consumers) ----------
__global__ void k_scan1(const int* __restrict__ cnt, int* __restrict__ excl,
                        int* __restrict__ bsum, int n) {
    __shared__ int sh[SCAN_B];
    int tid = threadIdx.x;
    int i = blockIdx.x * SCAN_B + tid;
    int v = (i < n) ? cnt[i] : 0;
    sh[tid] = v;
    __syncthreads();
    for (int off = 1; off < SCAN_B; off <<= 1) {
        int t = (tid >= off) ? sh[tid - off] : 0;
        __syncthreads();
        sh[tid] += t;
        __syncthreads();
    }
    if (i < n) excl[i] = sh[tid] - v;
    if (tid == SCAN_B - 1) bsum[blockIdx.x] = sh[tid];
}

__global__ void k_scan2(int* __restrict__ bsum, int nb) {
    __shared__ int sh[SCAN_B];
    int tid = threadIdx.x;
    int v = (tid < nb) ? bsum[tid] : 0;
    sh[tid] = v;
    __syncthreads();
    for (int off = 1; off < SCAN_B; off <<= 1) {
        int t = (tid >= off) ? sh[tid - off] : 0;
        __syncthreads();
        sh[tid] += t;
        __syncthreads();
    }
    if (tid < nb) bsum[tid] = sh[tid] - v;   // exclusive over block totals
}

// ---------- per-node meta: {rowstart:32, cnt:16, diag(fp16):16} packed u64 ----------
__global__ void k_meta(const int* __restrict__ excl, const int* __restrict__ bsum,
                       const int* __restrict__ cntd, const float* __restrict__ diag,
                       u64* __restrict__ meta, int n) {
    int i = blockIdx.x * 256 + threadIdx.x;
    if (i >= n) return;
    unsigned start = (unsigned)(excl[i] + bsum[i >> 8]);
    union { h16 h; unsigned short u; } d;
    d.h = (h16)diag[i];
    meta[i] = (u64)start | ((u64)(unsigned)cntd[i] << 32) | ((u64)d.u << 48);
}

// ---------- CSR fill, zero global atomics (bases from scanned dst partials) ----------
// Edge record = u32 {src:16, w:fp16:16} (halves csr bytes AND scattered-write
// line amplification vs the u64 record). rowstart[d] = excl[d] + bsum[d>>8].
__global__ __launch_bounds__(256) void k_fillcsr2(
    const int* __restrict__ src, const int* __restrict__ dst,
    const float* __restrict__ qs, const float* __restrict__ dis,
    const int* __restrict__ excl, const int* __restrict__ bsum,
    const unsigned* __restrict__ hpart, unsigned* __restrict__ csr, int E) {
    __shared__ unsigned lrank[HB];
    int tid = threadIdx.x;
    int e0 = blockIdx.x * PER_B;
    int vs[13], vd[13];
#pragma unroll
    for (int j = 0; j < 13; ++j) {
        int o = j * 256 + tid;
        vs[j] = (o < PER_B) ? src[e0 + o] : -1;
        vd[j] = (o < PER_B) ? dst[e0 + o] : -1;
    }
#pragma unroll
    for (int pass = 0; pass < 2; ++pass) {
        for (int t = tid; t < HB; t += 256) lrank[t] = 0;
        __syncthreads();
        int lo = pass * (2 * HB);
        const unsigned* base = hpart + ((size_t)pass * 256 + blockIdx.x) * HB;
#pragma unroll
        for (int j = 0; j < 13; ++j) {
            int vv = vd[j] - lo;
            if (vv >= 0 && vv < 2 * HB) {
                unsigned old = atomicAdd(&lrank[vv >> 1], (vv & 1) ? 0x10000u : 1u);
                unsigned rank = (vv & 1) ? (old >> 16) : (old & 0xffffu);
                unsigned bs = base[vv >> 1];
                unsigned bb = (vv & 1) ? (bs >> 16) : (bs & 0xffffu);
                int s = vs[j], d = vd[j];
                int pos = excl[d] + bsum[d >> 8] + (int)bb + (int)rank;
                union { h16 h; unsigned short u; } cw;
                cw.h = (h16)(qs[s] * dis[d]);
                csr[pos] = (unsigned)s | ((unsigned)cw.u << 16);
            }
        }
        __syncthreads();
    }
}

// ---------- W pre-transpose (Chebyshev fold) + x fp32->fp16 + hi0 pad-col zeroing ----------
// out = Tx0*(W0-W2) + Tx1*W1 + prop(Tx1)*(2*W2): gathers are pure props.
// fp16 [seg][ks][208][32]; B k-pads ZERO; hi0 cols [200,224) zeroed once so layer-1
// gather input pads are finite (A-pad x B-zero stays zero in MFMA).
__global__ void k_wprep(const float* __restrict__ W1, const float* __restrict__ W2,
                        const float* __restrict__ W3, const float* __restrict__ W4,
                        h16* __restrict__ wt0, h16* __restrict__ wt1,
                        h16* __restrict__ wt2, h16* __restrict__ wt3,
                        const float* __restrict__ x, h16* __restrict__ x16,
                        h16* __restrict__ hi0) {
    const int T0 = 3 * 2 * 208 * 32, T = 3 * 7 * 208 * 32;
    const int TW = T0 + 3 * T;
    int idx = blockIdx.x * blockDim.x + threadIdx.x;
    if (idx >= TW) {
        int i = idx - TW;
        if (i < NN * FIN) { x16[i] = (h16)x[i]; return; }
        int i2 = i - NN * FIN;                 // hi0 pad cols [200,224)
        if (i2 < MP * 24) {
            int row = i2 / 24;
            hi0[(size_t)row * KPAD + 200 + (i2 - row * 24)] = (h16)0.f;
        }
        return;
    }
    const float* W; h16* o; int fin, ksteps, li;
    if (idx < T0) { W = W1; o = wt0; fin = FIN; ksteps = 2; li = idx; }
    else {
        int r = idx - T0; int l = r / T;
        li = r - l * T; fin = HD; ksteps = 7;
        W = (l == 0) ? W2 : ((l == 1) ? W3 : W4);
        o = (l == 0) ? wt1 : ((l == 1) ? wt2 : wt3);
    }
    int kk = li & 31;
    int r2 = li >> 5;
    int nn = r2 % 208;
    int r3 = r2 / 208;
    int ks = r3 % ksteps;
    int seg = r3 / ksteps;
    int k = ks * 32 + kk;
    float val = 0.f;
    if (nn < HD && k < fin) {
        size_t base = (size_t)k * HD + nn;
        size_t segsz = (size_t)fin * HD;
        if (seg == 0)      val = W[base] - W[2 * segsz + base];   // W0 - W2
        else if (seg == 1) val = W[segsz + base];                 // W1
        else               val = 2.f * W[2 * segsz + base];       // 2*W2
    }
    o[li] = (h16)val;
}

// ---------- propagation: R0's proven structure + verified byte trims ----------
// Fetch-byte-bound at ~3.5 TB/s (R0-R3, invariant); slicing dead (3/3). Levers
// kept: u32 csr, packed meta (1 load), weight-fold (pure prop, no h0 stream).
__global__ __launch_bounds__(256) void k_gather(
    const u64* __restrict__ meta, const unsigned* __restrict__ csr,
    const h16* __restrict__ hin16, h16* __restrict__ hout16,
    int s16, int lsh, int n) {
    int per = 256 >> lsh;
    int i = blockIdx.x * per + (threadIdx.x >> lsh);
    if (i >= n) return;
    int lane = threadIdx.x & ((1 << lsh) - 1);
    int c0 = lane * 4;
    if (c0 >= s16) return;                    // lsh=6, s16=224: lanes 56-63 idle
    unsigned su = (unsigned)s16;
    union U { uint2 u; h16 h[4]; };
    union W16 { unsigned short u; h16 h; };
    u64 m = __builtin_nontemporal_load(&meta[i]);
    int start = (int)(unsigned)(m & 0xffffffffu);
    int cnt = (int)((m >> 32) & 0xffffu);
    W16 dg16; dg16.u = (unsigned short)(m >> 48);
    float dg = (float)dg16.h;
    const unsigned* cp = csr + start;
    float g0 = 0.f, g1 = 0.f, g2 = 0.f, g3 = 0.f;
    int k = 0;
    for (; k + 7 < cnt; k += 8) {
        unsigned e[8];
#pragma unroll
        for (int j = 0; j < 8; ++j) e[j] = __builtin_nontemporal_load(&cp[k + j]);
        U p[8];
#pragma unroll
        for (int j = 0; j < 8; ++j)                              // 8 rows in flight
            p[j].u = *(const uint2*)(hin16 + (size_t)((e[j] & 0xffffu) * su + (unsigned)c0));
#pragma unroll
        for (int j = 0; j < 8; ++j) {
            W16 wv; wv.u = (unsigned short)(e[j] >> 16);
            float w = (float)wv.h;
            g0 += w * (float)p[j].h[0];
            g1 += w * (float)p[j].h[1];
            g2 += w * (float)p[j].h[2];
            g3 += w * (float)p[j].h[3];
        }
    }
    for (; k + 1 < cnt; k += 2) {
        unsigned e0 = __builtin_nontemporal_load(&cp[k]);
        unsigned e1 = __builtin_nontemporal_load(&cp[k + 1]);
        U p0, p1;
        p0.u = *(const uint2*)(hin16 + (size_t)((e0 & 0xffffu) * su + (unsigned)c0));
        p1.u = *(const uint2*)(hin16 + (size_t)((e1 & 0xffffu) * su + (unsigned)c0));
        W16 w0v, w1v; w0v.u = (unsigned short)(e0 >> 16); w1v.u = (unsigned short)(e1 >> 16);
        float w0 = (float)w0v.h, w1 = (float)w1v.h;
        g0 += w0 * (float)p0.h[0] + w1 * (float)p1.h[0];
        g1 += w0 * (float)p0.h[1] + w1 * (float)p1.h[1];
        g2 += w0 * (float)p0.h[2] + w1 * (float)p1.h[2];
        g3 += w0 * (float)p0.h[3] + w1 * (float)p1.h[3];
    }
    if (k < cnt) {
        unsigned e0 = __builtin_nontemporal_load(&cp[k]);
        U p0;
        p0.u = *(const uint2*)(hin16 + (size_t)((e0 & 0xffffu) * su + (unsigned)c0));
        W16 w0v; w0v.u = (unsigned short)(e0 >> 16);
        float w0 = (float)w0v.h;
        g0 += w0 * (float)p0.h[0];
        g1 += w0 * (float)p0.h[1];
        g2 += w0 * (float)p0.h[2];
        g3 += w0 * (float)p0.h[3];
    }
    U hs; hs.u = *(const uint2*)(hin16 + (size_t)((unsigned)i * su + (unsigned)c0));
    U o;
    o.h[0] = (h16)(g0 + dg * (float)hs.h[0]);
    o.h[1] = (h16)(g1 + dg * (float)hs.h[1]);
    o.h[2] = (h16)(g2 + dg * (float)hs.h[2]);
    o.h[3] = (h16)(g3 + dg * (float)hs.h[3]);
    *(uint2*)(hout16 + (size_t)((unsigned)i * su + (unsigned)c0)) = o.u;
}

// ---------- MFMA fp16 GEMM, barrier-free: out = relu([A0|A1|A2] @ W + b) ----------
__global__ __launch_bounds__(256) void k_gemm16(
    const h16* __restrict__ A0, const h16* __restrict__ A1, const h16* __restrict__ A2,
    int strideA, int ksteps,
    const h16* __restrict__ Wt, const float* __restrict__ bias,
    h16* __restrict__ out16, int n) {
    int tid = threadIdx.x;
    int wave = tid >> 6, lane = tid & 63;
    int nq = lane & 15, quad = lane >> 4;
    int row0 = (blockIdx.x * 4 + wave) * 32;
    const h16* Aseg[3] = {A0, A1, A2};

    float4v acc[2][NT];
#pragma unroll
    for (int r = 0; r < 2; r++)
#pragma unroll
        for (int t = 0; t < NT; t++) acc[r][t] = (float4v)0.f;

    for (int seg = 0; seg < 3; ++seg) {
        const h16* Ab = Aseg[seg] + (size_t)(row0 + nq) * strideA + quad * 8;
        const h16* Bb = Wt + (size_t)seg * ksteps * 208 * 32 + (size_t)nq * 32 + quad * 8;
        for (int ks = 0; ks < ksteps; ++ks) {
            half8 af0 = *(const half8*)(Ab + ks * 32);
            half8 af1 = *(const half8*)(Ab + 16 * strideA + ks * 32);
            const h16* Bk = Bb + (size_t)ks * 208 * 32;
#pragma unroll
            for (int t = 0; t < NT; ++t) {
                half8 bf = *(const half8*)(Bk + t * 16 * 32);
                acc[0][t] = __builtin_amdgcn_mfma_f32_16x16x32_f16(af0, bf, acc[0][t], 0, 0, 0);
                acc[1][t] = __builtin_amdgcn_mfma_f32_16x16x32_f16(af1, bf, acc[1][t], 0, 0, 0);
            }
        }
    }
#pragma unroll
    for (int r = 0; r < 2; ++r) {
        int rowb = row0 + r * 16 + quad * 4;
#pragma unroll
        for (int t = 0; t < NT; ++t) {
            int col = t * 16 + nq;
            if (col >= HD) continue;
            float bj = bias[col];
#pragma unroll
            for (int g = 0; g < 4; ++g) {
                int row = rowb + g;
                if (row < n)
                    out16[(size_t)row * KPAD + col] = (h16)fmaxf(acc[r][t][g] + bj, 0.0f);
            }
        }
    }
}

// ---------- fused segmented pool (mean+max) + FC + log_softmax (fp16 input) ----------
__global__ __launch_bounds__(256) void k_pool_fc(
    const h16* __restrict__ Hf, const int* __restrict__ gstart,
    const float* __restrict__ fcw, const float* __restrict__ fcb,
    float* __restrict__ out) {
    __shared__ float red[8];
    int g = blockIdx.x;
    int j = threadIdx.x;
    int i0 = gstart[g], i1 = gstart[g + 1];
    float s0 = 0.f, s1 = 0.f, s2 = 0.f, s3 = 0.f, mx = 0.f;   // post-ReLU: max >= 0
    if (j < HD) {
        int i = i0;
        for (; i + 3 < i1; i += 4) {
            float v0 = (float)Hf[(size_t)i * KPAD + j];
            float v1 = (float)Hf[(size_t)(i + 1) * KPAD + j];
            float v2 = (float)Hf[(size_t)(i + 2) * KPAD + j];
            float v3 = (float)Hf[(size_t)(i + 3) * KPAD + j];
            s0 += v0; s1 += v1; s2 += v2; s3 += v3;
            mx = fmaxf(mx, fmaxf(fmaxf(v0, v1), fmaxf(v2, v3)));
        }
        for (; i < i1; ++i) {
            float v = (float)Hf[(size_t)i * KPAD + j];
            s0 += v; mx = fmaxf(mx, v);
        }
    }
    float cntf = (float)(i1 - i0);
    float mean = (s0 + s1 + s2 + s3) / fmaxf(cntf, 1.f);
    float p0 = 0.f, p1 = 0.f;
    if (j < HD) {
        p0 = mean * fcw[2 * j]     + mx * fcw[2 * (HD + j)];
        p1 = mean * fcw[2 * j + 1] + mx * fcw[2 * (HD + j) + 1];
    }
#pragma unroll
    for (int o = 32; o > 0; o >>= 1) {
        p0 += __shfl_down(p0, o);
        p1 += __shfl_down(p1, o);
    }
    int wave = j >> 6, lane = j & 63;
    if (lane == 0) { red[wave * 2] = p0; red[wave * 2 + 1] = p1; }
    __syncthreads();
    if (j == 0) {
        float z0 = red[0] + red[2] + red[4] + red[6] + fcb[0];
        float z1 = red[1] + red[3] + red[5] + red[7] + fcb[1];
        float m = fmaxf(z0, z1);
        float lse = m + logf(expf(z0 - m) + expf(z1 - m));
        out[g * 2 + 0] = z0 - lse;
        out[g * 2 + 1] = z1 - lse;
    }
}

extern "C" void kernel_launch(void* const* d_in, const int* in_sizes, int n_in,
                              void* d_out, int out_size, void* d_ws, size_t ws_size,
                              hipStream_t stream) {
    const float* x     = (const float*)d_in[0];
    const int*   edge  = (const int*)d_in[1];
    const int*   batch = (const int*)d_in[2];
    const float* lmax  = (const float*)d_in[3];
    const float* W1 = (const float*)d_in[4];  const float* b1 = (const float*)d_in[5];
    const float* W2 = (const float*)d_in[6];  const float* b2 = (const float*)d_in[7];
    const float* W3 = (const float*)d_in[8];  const float* b3 = (const float*)d_in[9];
    const float* W4 = (const float*)d_in[10]; const float* b4 = (const float*)d_in[11];
    const float* fcw = (const float*)d_in[12]; const float* fcb = (const float*)d_in[13];
    float* out = (float*)d_out;

    const int n = NN, E = NE;
    const int* src = edge;
    const int* dst = edge + E;

    // workspace layout (float units, each buffer 16B-aligned)
    float* ws = (float*)d_ws;
    size_t off = 0;
    auto alloc = [&](size_t nfloats) { float* p = ws + off; off += (nfloats + 3) & ~(size_t)3; return p; };
    int*   degi   = (int*)alloc(NN);
    float* dis    = alloc(NN);
    float* qs     = alloc(NN);
    float* diag   = alloc(NN);
    int*   cntd   = (int*)alloc(NN);
    int*   excl   = (int*)alloc(NN);
    int*   bsum   = (int*)alloc(SCAN_B);
    unsigned* csr = (unsigned*)alloc(NE);                   // packed {src:16, w:fp16}
    u64*   meta   = (u64*)alloc((size_t)2 * NN);            // {start:32, cnt:16, diag:16}
    int*   gstart = (int*)alloc(NG + 1);
    unsigned* pSrc = (unsigned*)alloc((size_t)2 * 256 * HB);  // src histogram partials
    unsigned* pDst = (unsigned*)alloc((size_t)2 * 256 * HB);  // dst histogram partials/bases
    h16*   x16    = (h16*)alloc((size_t)MP * FIN / 2);      // fp16 x (stride 64)
    h16*   hi0    = (h16*)alloc((size_t)MP * KPAD / 2);     // fp16 h (inter-layer, in-place)
    h16*   hi1    = (h16*)alloc((size_t)MP * KPAD / 2);     // fp16 Tx1 / final features
    h16*   hi2    = (h16*)alloc((size_t)MP * KPAD / 2);     // fp16 P2 = prop(Tx1)
    const int WSZ0 = 3 * 2 * 208 * 32;
    const int WSZ  = 3 * 7 * 208 * 32;
    h16* wt0 = (h16*)alloc(WSZ0 / 2);
    h16* wt1 = (h16*)alloc(WSZ / 2);
    h16* wt2 = (h16*)alloc(WSZ / 2);
    h16* wt3 = (h16*)alloc(WSZ / 2);

    dim3 blk(256);
    int gN = (n + 255) / 256;
    int gScan = (n + SCAN_B - 1) / SCAN_B;      // 196
    int gGemm = MP / 128;                       // 391 blocks, 4 waves x 32 rows
    int gWp = (WSZ0 + 3 * WSZ + NN * FIN + MP * 24 + 255) / 256;

    // --- setup (histogram pipeline: zero global atomics; R5 showed device
    //     atomics cost 72.7 us in k_fill alone) ---
    k_wprep<<<gWp, blk, 0, stream>>>(W1, W2, W3, W4, wt0, wt1, wt2, wt3, x, x16, hi0);
    k_hist<<<512, blk, 0, stream>>>(src, dst, pSrc, pDst, E);
    k_hredscan<<<(4 * HB + 255) / 256, blk, 0, stream>>>(pSrc, pDst, degi, cntd, n);
    k_prep<<<gN + 2, blk, 0, stream>>>(degi, batch, lmax, dis, qs, diag, gstart, n, gN);
    k_scan1<<<gScan, blk, 0, stream>>>(cntd, excl, bsum, n);
    k_scan2<<<1, blk, 0, stream>>>(bsum, gScan);
    k_meta<<<gScan, blk, 0, stream>>>(excl, bsum, cntd, diag, meta, n);
    k_fillcsr2<<<256, blk, 0, stream>>>(src, dst, qs, dis, excl, bsum, pDst, csr, E);

    // --- 4 Chebyshev layers (R0-structure gathers + MFMA gemm) ---
    const h16* wt[4] = {wt0, wt1, wt2, wt3};
    const float* bl[4] = {b1, b2, b3, b4};
    for (int l = 0; l < 4; l++) {
        int s16 = (l == 0) ? FIN : KPAD;
        int lsh = (l == 0) ? 4 : 6;              // 16-lane groups (l0) / full wave
        int per = 256 >> lsh;
        int gGat = (n + per - 1) / per;
        int ksteps = (l == 0) ? 2 : 7;
        const h16* a0 = (l == 0) ? x16 : hi0;
        // Tx1 = prop(Tx0) -> hi1
        k_gather<<<gGat, blk, 0, stream>>>(meta, csr, a0, hi1, s16, lsh, n);
        // P2 = prop(Tx1) -> hi2   (Chebyshev 2x / -Tx0 folded into weights)
        k_gather<<<gGat, blk, 0, stream>>>(meta, csr, hi1, hi2, s16, lsh, n);
        // out = relu(Tx0@(W0-W2) + Tx1@W1 + P2@(2W2) + b) -> hi0 (layers 0-2) or hi1 (final)
        k_gemm16<<<gGemm, blk, 0, stream>>>(a0, hi1, hi2, s16, ksteps, wt[l], bl[l],
                                            (l < 3) ? hi0 : hi1, n);
    }

    // --- fused pool + FC head (no atomics; batch is sorted; fp16 input) ---
    k_pool_fc<<<NG, blk, 0, stream>>>(hi1, gstart, fcw, fcb, out);
}